// Round 1
// baseline (1127.841 us; speedup 1.0000x reference)
//
#include <hip/hip_runtime.h>

// Problem constants (fixed by the reference)
#define T_TOK 4096   // B*S tokens
#define DIM   1024   // model dim D
#define HID   1024   // expert hidden H
#define NEXP  16     // routed experts
#define HSH   2048   // shared hidden = NSH*H
#define NIN   2      // experts that consume x instead of emb

typedef __attribute__((ext_vector_type(8))) short bf8_t;  // 8 x bf16 (MFMA A/B frag)
typedef __attribute__((ext_vector_type(4))) float f4_t;   // 4 x f32  (MFMA C/D frag)

__device__ __forceinline__ ushort f2b(float f) {  // f32 -> bf16 RNE
  unsigned u = __float_as_uint(f);
  u = (u + 0x7FFFu + ((u >> 16) & 1u)) >> 16;
  return (ushort)u;
}

// chunk-XOR swizzle for the B^T [n][k] LDS tile: avoids 16-way bank conflicts
// on the pair-packed b32 staging writes (keeps 8-elem k-chunks contiguous so
// frag reads stay ds_read_b128).
__device__ __forceinline__ int bcol(int n, int k) {
  return (((k >> 3) ^ ((n >> 3) & 3)) << 3) + (k & 7);
}

// ---------------------------------------------------------------------------
// Core 128x128 (BK=32) bf16 MFMA GEMM: C[128,128] += A[128,K] * W[K, NG-slice]
// A rows given per-thread (gather handled by caller). W is row-major [K][NG].
// 4 waves, each computing a 64x64 quadrant via 16x16x32 MFMA.
// DUAL=true additionally computes A*W3 into acc3 (for fused SwiGLU W1/W3).
// ---------------------------------------------------------------------------
template<int NG, int KD, bool DUAL>
__device__ __forceinline__ void gemm_core(
    const ushort* __restrict__ arow0, const ushort* __restrict__ arow1,
    const ushort* __restrict__ Wb1, const ushort* __restrict__ Wb3, int n0,
    ushort* As, ushort* Bs1, ushort* Bs3,
    f4_t acc1[4][4], f4_t acc3[4][4])
{
  const int tid  = threadIdx.x;
  const int lane = tid & 63;
  const int wave = tid >> 6;
  const int wm = wave & 1, wn = wave >> 1;
  const int quad = lane >> 4, lr = lane & 15;
  const int r0  = tid >> 2;          // A stage: row (2 rows per thread: r0, r0+64)
  const int kc0 = (tid & 3) << 3;    // A stage: k chunk
  const int n8  = (tid & 15) << 3;   // B stage: 8 consecutive n
  const int kk  = (tid >> 4) << 1;   // B stage: k pair (kk, kk+1)

  const ushort* wp1 = Wb1 + (size_t)kk * NG + n0 + n8;
  const ushort* wp3 = DUAL ? (Wb3 + (size_t)kk * NG + n0 + n8) : wp1;

  for (int k0 = 0; k0 < KD; k0 += 32) {
    // ---- stage A [128 x 32] (row-major, stride 40 for bank spread)
    uint4 av0 = *(const uint4*)(arow0 + k0);
    uint4 av1 = *(const uint4*)(arow1 + k0);
    // ---- load B rows kk, kk+1 (8 n each) for pair-packing
    const ushort* p1 = wp1 + (size_t)k0 * NG;
    uint4 g0 = *(const uint4*)(p1);
    uint4 g1 = *(const uint4*)(p1 + NG);
    uint4 h0, h1;
    if (DUAL) {
      const ushort* p3 = wp3 + (size_t)k0 * NG;
      h0 = *(const uint4*)(p3);
      h1 = *(const uint4*)(p3 + NG);
    }
    *(uint4*)&As[r0 * 40 + kc0] = av0;
    *(uint4*)&As[(r0 + 64) * 40 + kc0] = av1;
    {
      const ushort* a = (const ushort*)&g0;
      const ushort* b = (const ushort*)&g1;
      #pragma unroll
      for (int j = 0; j < 8; j++) {
        unsigned v = (unsigned)a[j] | ((unsigned)b[j] << 16);
        *(unsigned*)&Bs1[(n8 + j) * 40 + bcol(n8 + j, kk)] = v;
      }
    }
    if (DUAL) {
      const ushort* a = (const ushort*)&h0;
      const ushort* b = (const ushort*)&h1;
      #pragma unroll
      for (int j = 0; j < 8; j++) {
        unsigned v = (unsigned)a[j] | ((unsigned)b[j] << 16);
        *(unsigned*)&Bs3[(n8 + j) * 40 + bcol(n8 + j, kk)] = v;
      }
    }
    __syncthreads();
    // ---- compute
    bf8_t af[4];
    #pragma unroll
    for (int mi = 0; mi < 4; mi++)
      af[mi] = *(const bf8_t*)&As[(wm * 64 + mi * 16 + lr) * 40 + quad * 8];
    #pragma unroll
    for (int ni = 0; ni < 4; ni++) {
      const int nn = wn * 64 + ni * 16 + lr;
      bf8_t bf1 = *(const bf8_t*)&Bs1[nn * 40 + bcol(nn, quad * 8)];
      #pragma unroll
      for (int mi = 0; mi < 4; mi++)
        acc1[mi][ni] = __builtin_amdgcn_mfma_f32_16x16x32_bf16(af[mi], bf1, acc1[mi][ni], 0, 0, 0);
      if (DUAL) {
        bf8_t bf3 = *(const bf8_t*)&Bs3[nn * 40 + bcol(nn, quad * 8)];
        #pragma unroll
        for (int mi = 0; mi < 4; mi++)
          acc3[mi][ni] = __builtin_amdgcn_mfma_f32_16x16x32_bf16(af[mi], bf3, acc3[mi][ni], 0, 0, 0);
      }
    }
    __syncthreads();
  }
}

// ---------------------------------------------------------------------------
// fp32 -> bf16 conversion of emb, x, W1, W3, W2, sW1, sW2 into one contiguous
// bf16 workspace region (same order, so dst index == global element index).
// ---------------------------------------------------------------------------
__global__ void convert_all(const float* __restrict__ e_, const float* __restrict__ x_,
                            const float* __restrict__ w1_, const float* __restrict__ w3_,
                            const float* __restrict__ w2_, const float* __restrict__ s1_,
                            const float* __restrict__ s2_, ushort* __restrict__ dst)
{
  const long long NQ = 15728640LL;  // 62,914,560 elems / 4
  const long long stride = (long long)gridDim.x * blockDim.x;
  for (long long q = (long long)blockIdx.x * blockDim.x + threadIdx.x; q < NQ; q += stride) {
    long long i = q << 2;
    const float* src; long long base;
    if      (i <  4194304LL) { src = e_;  base = 0LL;        }
    else if (i <  8388608LL) { src = x_;  base = 4194304LL;  }
    else if (i < 25165824LL) { src = w1_; base = 8388608LL;  }
    else if (i < 41943040LL) { src = w3_; base = 25165824LL; }
    else if (i < 58720256LL) { src = w2_; base = 41943040LL; }
    else if (i < 60817408LL) { src = s1_; base = 58720256LL; }
    else                     { src = s2_; base = 60817408LL; }
    const float4 v = *(const float4*)(src + (i - base));
    ushort4 o;
    o.x = f2b(v.x); o.y = f2b(v.y); o.z = f2b(v.z); o.w = f2b(v.w);
    *(ushort4*)(dst + i) = o;
  }
}

// ---------------------------------------------------------------------------
// Gate: fp32 scores = softmax(emb @ gate_w^T), top-2, build per-expert
// compacted token lists via atomic counters. One block per token.
// ---------------------------------------------------------------------------
__global__ void gate_topk(const float* __restrict__ emb, const float* __restrict__ gw,
                          int* __restrict__ cnt, int* __restrict__ list, float* __restrict__ wl)
{
  __shared__ float se[DIM];
  __shared__ float sc[NEXP];
  const int tok = blockIdx.x;
  const int t = threadIdx.x;
  const float* row = emb + (size_t)tok * DIM;
  for (int i = t; i < DIM; i += 256) se[i] = row[i];
  __syncthreads();
  const int e = t >> 4, l = t & 15;
  float p = 0.f;
  const float* g = gw + e * DIM;
  for (int i = l; i < DIM; i += 16) p += se[i] * g[i];
  p += __shfl_xor(p, 1); p += __shfl_xor(p, 2);
  p += __shfl_xor(p, 4); p += __shfl_xor(p, 8);
  if (l == 0) sc[e] = p;
  __syncthreads();
  if (t == 0) {
    float m = sc[0];
    #pragma unroll
    for (int j = 1; j < NEXP; j++) m = fmaxf(m, sc[j]);
    float pr[NEXP]; float s = 0.f;
    #pragma unroll
    for (int j = 0; j < NEXP; j++) { pr[j] = expf(sc[j] - m); s += pr[j]; }
    const float inv = 1.0f / s;
    int i0 = 0; float b0 = pr[0];
    #pragma unroll
    for (int j = 1; j < NEXP; j++) if (pr[j] > b0) { b0 = pr[j]; i0 = j; }
    int i1 = -1; float b1 = -1.f;
    #pragma unroll
    for (int j = 0; j < NEXP; j++) if (j != i0 && pr[j] > b1) { b1 = pr[j]; i1 = j; }
    const int p0 = atomicAdd(&cnt[i0], 1);
    list[i0 * T_TOK + p0] = tok; wl[i0 * T_TOK + p0] = b0 * inv;
    const int p1 = atomicAdd(&cnt[i1], 1);
    list[i1 * T_TOK + p1] = tok; wl[i1 * T_TOK + p1] = b1 * inv;
  }
}

__global__ void scan_offs(const int* __restrict__ cnt, int* __restrict__ offs)
{
  if (blockIdx.x == 0 && threadIdx.x == 0) {
    int a = 0;
    for (int e = 0; e < NEXP; e++) { offs[e] = a; a += cnt[e]; }
    offs[NEXP] = a;
  }
}

// ---------------------------------------------------------------------------
// Routed FFN stage 1: h = silu(A@W1 + B1) * (A@W3 + B3), A rows gathered per
// expert token list, h stored compacted (offs[e] + pos) as bf16.
// ---------------------------------------------------------------------------
__launch_bounds__(256, 2)
__global__ void moe_ffn1(const ushort* __restrict__ embb, const ushort* __restrict__ xb,
                         const ushort* __restrict__ w1b, const ushort* __restrict__ w3b,
                         const float* __restrict__ B1, const float* __restrict__ B3,
                         const int* __restrict__ cnt, const int* __restrict__ offs,
                         const int* __restrict__ list, ushort* __restrict__ hb)
{
  const int e = blockIdx.z;
  const int ce = cnt[e];
  const int m0 = blockIdx.x * 128;
  if (m0 >= ce) return;
  const int n0 = blockIdx.y * 128;
  const int off = offs[e];
  const ushort* Ab = (e < NIN) ? xb : embb;

  __shared__ ushort As[128 * 40];
  __shared__ ushort Bs1[128 * 40];
  __shared__ ushort Bs3[128 * 40];

  const int tid = threadIdx.x;
  const int r0 = tid >> 2;
  const int kc0 = (tid & 3) << 3;
  const int li = e * T_TOK;
  const int i0 = min(m0 + r0, ce - 1);
  const int i1 = min(m0 + 64 + r0, ce - 1);
  const ushort* arow0 = Ab + (size_t)list[li + i0] * DIM + kc0;
  const ushort* arow1 = Ab + (size_t)list[li + i1] * DIM + kc0;

  f4_t acc1[4][4], acc3[4][4];
  const f4_t fz = {0.f, 0.f, 0.f, 0.f};
  #pragma unroll
  for (int i = 0; i < 4; i++)
    #pragma unroll
    for (int j = 0; j < 4; j++) { acc1[i][j] = fz; acc3[i][j] = fz; }

  gemm_core<HID, DIM, true>(arow0, arow1,
      w1b + (size_t)e * DIM * HID, w3b + (size_t)e * DIM * HID, n0,
      As, Bs1, Bs3, acc1, acc3);

  const int lane = tid & 63, wave = tid >> 6;
  const int wm = wave & 1, wn = wave >> 1;
  const int quad = lane >> 4, lr = lane & 15;
  #pragma unroll
  for (int mi = 0; mi < 4; mi++) {
    #pragma unroll
    for (int r = 0; r < 4; r++) {
      const int rowl = m0 + wm * 64 + mi * 16 + quad * 4 + r;
      if (rowl < ce) {
        ushort* hr = hb + (size_t)(off + rowl) * HID;
        #pragma unroll
        for (int ni = 0; ni < 4; ni++) {
          const int col = n0 + wn * 64 + ni * 16 + lr;
          const float v1 = acc1[mi][ni][r] + B1[e * HID + col];
          const float v3 = acc3[mi][ni][r] + B3[e * HID + col];
          const float sg = 1.0f / (1.0f + __expf(-v1));
          hr[col] = f2b(v1 * sg * v3);
        }
      }
    }
  }
}

// ---------------------------------------------------------------------------
// Routed FFN stage 2: y[tok] += w * (h_e @ W2 + B2) via fp32 atomics.
// ---------------------------------------------------------------------------
__launch_bounds__(256, 2)
__global__ void moe_ffn2(const ushort* __restrict__ hb, const ushort* __restrict__ w2b,
                         const float* __restrict__ B2,
                         const int* __restrict__ cnt, const int* __restrict__ offs,
                         const int* __restrict__ list, const float* __restrict__ wl,
                         float* __restrict__ y)
{
  const int e = blockIdx.z;
  const int ce = cnt[e];
  const int m0 = blockIdx.x * 128;
  if (m0 >= ce) return;
  const int n0 = blockIdx.y * 128;
  const int off = offs[e];

  __shared__ ushort As[128 * 40];
  __shared__ ushort Bs[128 * 40];

  const int tid = threadIdx.x;
  const int r0 = tid >> 2;
  const int kc0 = (tid & 3) << 3;
  const int i0 = off + min(m0 + r0, ce - 1);
  const int i1 = off + min(m0 + 64 + r0, ce - 1);
  const ushort* arow0 = hb + (size_t)i0 * HID + kc0;
  const ushort* arow1 = hb + (size_t)i1 * HID + kc0;

  f4_t acc[4][4];
  const f4_t fz = {0.f, 0.f, 0.f, 0.f};
  #pragma unroll
  for (int i = 0; i < 4; i++)
    #pragma unroll
    for (int j = 0; j < 4; j++) acc[i][j] = fz;

  gemm_core<DIM, HID, false>(arow0, arow1, w2b + (size_t)e * HID * DIM, nullptr, n0,
                             As, Bs, Bs, acc, acc);

  const int lane = tid & 63, wave = tid >> 6;
  const int wm = wave & 1, wn = wave >> 1;
  const int quad = lane >> 4, lr = lane & 15;
  #pragma unroll
  for (int mi = 0; mi < 4; mi++) {
    #pragma unroll
    for (int r = 0; r < 4; r++) {
      const int rowl = m0 + wm * 64 + mi * 16 + quad * 4 + r;
      if (rowl < ce) {
        const int tok = list[e * T_TOK + rowl];
        const float w = wl[e * T_TOK + rowl];
        float* yr = y + (size_t)tok * DIM;
        #pragma unroll
        for (int ni = 0; ni < 4; ni++) {
          const int col = n0 + wn * 64 + ni * 16 + lr;
          atomicAdd(&yr[col], w * (acc[mi][ni][r] + B2[e * DIM + col]));
        }
      }
    }
  }
}

// ---------------------------------------------------------------------------
// Shared expert stage 1: hs = silu(emb @ sW1 + sB1)  [T x 2048] bf16
// ---------------------------------------------------------------------------
__launch_bounds__(256, 2)
__global__ void shared_ffn1(const ushort* __restrict__ embb, const ushort* __restrict__ sw1b,
                            const float* __restrict__ sB1, ushort* __restrict__ hsb)
{
  const int m0 = blockIdx.x * 128;
  const int n0 = blockIdx.y * 128;
  __shared__ ushort As[128 * 40];
  __shared__ ushort Bs[128 * 40];
  const int tid = threadIdx.x;
  const int r0 = tid >> 2;
  const int kc0 = (tid & 3) << 3;
  const ushort* arow0 = embb + (size_t)(m0 + r0) * DIM + kc0;
  const ushort* arow1 = embb + (size_t)(m0 + 64 + r0) * DIM + kc0;

  f4_t acc[4][4];
  const f4_t fz = {0.f, 0.f, 0.f, 0.f};
  #pragma unroll
  for (int i = 0; i < 4; i++)
    #pragma unroll
    for (int j = 0; j < 4; j++) acc[i][j] = fz;

  gemm_core<HSH, DIM, false>(arow0, arow1, sw1b, nullptr, n0, As, Bs, Bs, acc, acc);

  const int lane = tid & 63, wave = tid >> 6;
  const int wm = wave & 1, wn = wave >> 1;
  const int quad = lane >> 4, lr = lane & 15;
  #pragma unroll
  for (int mi = 0; mi < 4; mi++) {
    #pragma unroll
    for (int r = 0; r < 4; r++) {
      const int row = m0 + wm * 64 + mi * 16 + quad * 4 + r;
      ushort* hr = hsb + (size_t)row * HSH;
      #pragma unroll
      for (int ni = 0; ni < 4; ni++) {
        const int col = n0 + wn * 64 + ni * 16 + lr;
        const float v = acc[mi][ni][r] + sB1[col];
        const float sg = 1.0f / (1.0f + __expf(-v));
        hr[col] = f2b(v * sg);
      }
    }
  }
}

// ---------------------------------------------------------------------------
// Shared expert stage 2: y = hs @ sW2 + sB2 (plain store, initializes y)
// ---------------------------------------------------------------------------
__launch_bounds__(256, 2)
__global__ void shared_ffn2(const ushort* __restrict__ hsb, const ushort* __restrict__ sw2b,
                            const float* __restrict__ sB2, float* __restrict__ y)
{
  const int m0 = blockIdx.x * 128;
  const int n0 = blockIdx.y * 128;
  __shared__ ushort As[128 * 40];
  __shared__ ushort Bs[128 * 40];
  const int tid = threadIdx.x;
  const int r0 = tid >> 2;
  const int kc0 = (tid & 3) << 3;
  const ushort* arow0 = hsb + (size_t)(m0 + r0) * HSH + kc0;
  const ushort* arow1 = hsb + (size_t)(m0 + 64 + r0) * HSH + kc0;

  f4_t acc[4][4];
  const f4_t fz = {0.f, 0.f, 0.f, 0.f};
  #pragma unroll
  for (int i = 0; i < 4; i++)
    #pragma unroll
    for (int j = 0; j < 4; j++) acc[i][j] = fz;

  gemm_core<DIM, HSH, false>(arow0, arow1, sw2b, nullptr, n0, As, Bs, Bs, acc, acc);

  const int lane = tid & 63, wave = tid >> 6;
  const int wm = wave & 1, wn = wave >> 1;
  const int quad = lane >> 4, lr = lane & 15;
  #pragma unroll
  for (int mi = 0; mi < 4; mi++) {
    #pragma unroll
    for (int r = 0; r < 4; r++) {
      const int row = m0 + wm * 64 + mi * 16 + quad * 4 + r;
      float* yr = y + (size_t)row * DIM;
      #pragma unroll
      for (int ni = 0; ni < 4; ni++) {
        const int col = n0 + wn * 64 + ni * 16 + lr;
        yr[col] = acc[mi][ni][r] + sB2[col];
      }
    }
  }
}

// ---------------------------------------------------------------------------
// Launch
// ---------------------------------------------------------------------------
extern "C" void kernel_launch(void* const* d_in, const int* in_sizes, int n_in,
                              void* d_out, int out_size, void* d_ws, size_t ws_size,
                              hipStream_t stream)
{
  const float* emb = (const float*)d_in[0];
  const float* x   = (const float*)d_in[1];
  const float* gw  = (const float*)d_in[2];
  const float* W1  = (const float*)d_in[3];
  const float* B1  = (const float*)d_in[4];
  const float* W2  = (const float*)d_in[5];
  const float* B2  = (const float*)d_in[6];
  const float* W3  = (const float*)d_in[7];
  const float* B3  = (const float*)d_in[8];
  const float* sW1 = (const float*)d_in[9];
  const float* sB1 = (const float*)d_in[10];
  const float* sW2 = (const float*)d_in[11];
  const float* sB2 = (const float*)d_in[12];
  float* y = (float*)d_out;

  char* ws = (char*)d_ws;
  const size_t MB = 1024ULL * 1024ULL;
  // bf16 region (contiguous, in convert order): emb,x,W1,W3,W2,sW1,sW2
  ushort* emb_b = (ushort*)(ws + 0);
  ushort* x_b   = (ushort*)(ws + 8 * MB);
  ushort* w1_b  = (ushort*)(ws + 16 * MB);
  ushort* w3_b  = (ushort*)(ws + 48 * MB);
  ushort* w2_b  = (ushort*)(ws + 80 * MB);
  ushort* sw1_b = (ushort*)(ws + 112 * MB);
  ushort* sw2_b = (ushort*)(ws + 116 * MB);
  ushort* h_b   = (ushort*)(ws + 120 * MB);   // [8192 x 1024] bf16 compact
  ushort* hs_b  = (ushort*)(ws + 136 * MB);   // [4096 x 2048] bf16
  int*   cnt    = (int*)(ws + 152 * MB);      // [16]
  int*   offs   = cnt + 16;                   // [17]
  int*   list   = (int*)(ws + 152 * MB + 1024);            // [16][4096]
  float* wl     = (float*)(ws + 152 * MB + 1024 + 262144); // [16][4096]

  hipMemsetAsync(cnt, 0, 64, stream);
  convert_all<<<4096, 256, 0, stream>>>(emb, x, W1, W3, W2, sW1, sW2, emb_b);
  gate_topk<<<T_TOK, 256, 0, stream>>>(emb, gw, cnt, list, wl);
  scan_offs<<<1, 64, 0, stream>>>(cnt, offs);
  moe_ffn1<<<dim3(32, 8, NEXP), 256, 0, stream>>>(emb_b, x_b, w1_b, w3_b, B1, B3,
                                                  cnt, offs, list, h_b);
  shared_ffn1<<<dim3(32, 16), 256, 0, stream>>>(emb_b, sw1_b, sB1, hs_b);
  shared_ffn2<<<dim3(32, 8), 256, 0, stream>>>(hs_b, sw2_b, sB2, y);   // writes y
  moe_ffn2<<<dim3(32, 8, NEXP), 256, 0, stream>>>(h_b, w2_b, B2,
                                                  cnt, offs, list, wl, y); // += routed
}

// Round 2
// 1041.273 us; speedup vs baseline: 1.0831x; 1.0831x over previous
//
#include <hip/hip_runtime.h>

// Problem constants (fixed by the reference)
#define T_TOK 4096   // B*S tokens
#define DIM   1024   // model dim D
#define HID   1024   // expert hidden H
#define NEXP  16     // routed experts
#define HSH   2048   // shared hidden = NSH*H
#define NIN   2      // experts that consume x instead of emb

typedef __attribute__((ext_vector_type(8))) short bf8_t;  // 8 x bf16 (MFMA A/B frag)
typedef __attribute__((ext_vector_type(4))) float f4_t;   // 4 x f32  (MFMA C/D frag)

__device__ __forceinline__ ushort f2b(float f) {  // f32 -> bf16 RNE
  unsigned u = __float_as_uint(f);
  u = (u + 0x7FFFu + ((u >> 16) & 1u)) >> 16;
  return (ushort)u;
}

// Async global->LDS DMA, 16B per lane. LDS dest is WAVE-UNIFORM base;
// HW scatters lane i to base + i*16. Requires lane-contiguous LDS layout.
__device__ __forceinline__ void gl_lds16(const ushort* g, ushort* l) {
  __builtin_amdgcn_global_load_lds(
      (const __attribute__((address_space(1))) void*)g,
      (__attribute__((address_space(3))) void*)l, 16, 0, 0);
}

// ---------------------------------------------------------------------------
// m97-style K-loop: tiles [128 rows][32 k] unpadded in LDS, staged entirely by
// global_load_lds width=16 (2 instructions per wave per tile). All matrices
// (A and B) are [row][k] with row stride = K elements in global memory
// (B pre-transposed to [n][k] by the convert phase).
// Fragment reads: full-wave ds_read_b128 over a contiguous 1KB block ->
// conflict-free. 4 waves each compute a 64x64 quadrant via 16x16x32 MFMA.
// ---------------------------------------------------------------------------
template<int KD, bool DUAL>
__device__ __forceinline__ void mfma_loop(
    const ushort* __restrict__ ap0, const ushort* __restrict__ ap1,
    const ushort* __restrict__ bp0, const ushort* __restrict__ bp1,
    const ushort* __restrict__ cp0, const ushort* __restrict__ cp1,
    ushort* As, ushort* Bs1, ushort* Bs3,
    f4_t acc1[4][4], f4_t acc3[4][4], int tid)
{
  const int lane = tid & 63, w = tid >> 6;
  const int wm = w & 1, wn = w >> 1;
  const int quad = lane >> 4, lr = lane & 15;
  ushort* ldsA0 = As  + (2 * w)     * 512;   // 1KB chunk = 16 rows x 64B
  ushort* ldsA1 = As  + (2 * w + 1) * 512;
  ushort* ldsB0 = Bs1 + (2 * w)     * 512;
  ushort* ldsB1 = Bs1 + (2 * w + 1) * 512;
  ushort* ldsC0 = Bs3 + (2 * w)     * 512;
  ushort* ldsC1 = Bs3 + (2 * w + 1) * 512;

  for (int k0 = 0; k0 < KD; k0 += 32) {
    gl_lds16(ap0 + k0, ldsA0);
    gl_lds16(ap1 + k0, ldsA1);
    gl_lds16(bp0 + k0, ldsB0);
    gl_lds16(bp1 + k0, ldsB1);
    if (DUAL) {
      gl_lds16(cp0 + k0, ldsC0);
      gl_lds16(cp1 + k0, ldsC1);
    }
    __syncthreads();   // compiler emits vmcnt(0) drain before s_barrier
    bf8_t af[4];
    #pragma unroll
    for (int mi = 0; mi < 4; mi++)
      af[mi] = *(const bf8_t*)&As[(wm * 64 + mi * 16 + lr) * 32 + quad * 8];
    #pragma unroll
    for (int ni = 0; ni < 4; ni++) {
      const int nn = wn * 64 + ni * 16 + lr;
      bf8_t b1 = *(const bf8_t*)&Bs1[nn * 32 + quad * 8];
      #pragma unroll
      for (int mi = 0; mi < 4; mi++)
        acc1[mi][ni] = __builtin_amdgcn_mfma_f32_16x16x32_bf16(af[mi], b1, acc1[mi][ni], 0, 0, 0);
      if (DUAL) {
        bf8_t b3 = *(const bf8_t*)&Bs3[nn * 32 + quad * 8];
        #pragma unroll
        for (int mi = 0; mi < 4; mi++)
          acc3[mi][ni] = __builtin_amdgcn_mfma_f32_16x16x32_bf16(af[mi], b3, acc3[mi][ni], 0, 0, 0);
      }
    }
    __syncthreads();
  }
}

// ---------------------------------------------------------------------------
// emb + x: straight fp32 -> bf16 cast (A operands stay [token][k])
// ---------------------------------------------------------------------------
__global__ void cast_ax(const float* __restrict__ e_, const float* __restrict__ x_,
                        ushort* __restrict__ dst)
{
  const long long NQ = 2097152LL;  // 8M elems / 4
  const long long stride = (long long)gridDim.x * blockDim.x;
  for (long long q = (long long)blockIdx.x * blockDim.x + threadIdx.x; q < NQ; q += stride) {
    long long i = q << 2;
    const float* src = (i < 4194304LL) ? e_ : x_;
    long long base = (i < 4194304LL) ? 0LL : 4194304LL;
    const float4 v = *(const float4*)(src + (i - base));
    ushort4 o;
    o.x = f2b(v.x); o.y = f2b(v.y); o.z = f2b(v.z); o.w = f2b(v.w);
    *(ushort4*)(dst + i) = o;
  }
}

// ---------------------------------------------------------------------------
// Tiled transpose + cast: src fp32 [batch][R][C] -> dst bf16 [batch][C][R].
// 64x64 tile via LDS (stride 65 -> conflict-free both phases).
// ---------------------------------------------------------------------------
__global__ void transpose_cast(const float* __restrict__ src, ushort* __restrict__ dst,
                               int R, int C)
{
  __shared__ float t[64 * 65];
  const size_t mb = (size_t)blockIdx.z * R * C;
  const int r0 = blockIdx.y * 64, c0 = blockIdx.x * 64;
  const int tid = threadIdx.x;
  {
    const int row = tid >> 4;          // 0..15
    const int c4  = (tid & 15) * 4;
    #pragma unroll
    for (int p = 0; p < 4; p++) {
      const int r = p * 16 + row;
      const float4 v = *(const float4*)(src + mb + (size_t)(r0 + r) * C + c0 + c4);
      t[r * 65 + c4 + 0] = v.x; t[r * 65 + c4 + 1] = v.y;
      t[r * 65 + c4 + 2] = v.z; t[r * 65 + c4 + 3] = v.w;
    }
  }
  __syncthreads();
  {
    const int oc  = tid >> 2;          // out row = col c0+oc
    const int seg = (tid & 3) * 16;    // r segment
    ushort tmp[16];
    #pragma unroll
    for (int i = 0; i < 16; i++) tmp[i] = f2b(t[(seg + i) * 65 + oc]);
    ushort* d = dst + mb + (size_t)(c0 + oc) * R + r0 + seg;
    *(uint4*)(d)     = *(uint4*)&tmp[0];
    *(uint4*)(d + 8) = *(uint4*)&tmp[8];
  }
}

// ---------------------------------------------------------------------------
// Gate: fp32 scores = softmax(emb @ gate_w^T), top-2, per-expert compact lists
// ---------------------------------------------------------------------------
__global__ void gate_topk(const float* __restrict__ emb, const float* __restrict__ gw,
                          int* __restrict__ cnt, int* __restrict__ list, float* __restrict__ wl)
{
  __shared__ float se[DIM];
  __shared__ float sc[NEXP];
  const int tok = blockIdx.x;
  const int t = threadIdx.x;
  const float* row = emb + (size_t)tok * DIM;
  for (int i = t; i < DIM; i += 256) se[i] = row[i];
  __syncthreads();
  const int e = t >> 4, l = t & 15;
  float p = 0.f;
  const float* g = gw + e * DIM;
  for (int i = l; i < DIM; i += 16) p += se[i] * g[i];
  p += __shfl_xor(p, 1); p += __shfl_xor(p, 2);
  p += __shfl_xor(p, 4); p += __shfl_xor(p, 8);
  if (l == 0) sc[e] = p;
  __syncthreads();
  if (t == 0) {
    float m = sc[0];
    #pragma unroll
    for (int j = 1; j < NEXP; j++) m = fmaxf(m, sc[j]);
    float pr[NEXP]; float s = 0.f;
    #pragma unroll
    for (int j = 0; j < NEXP; j++) { pr[j] = expf(sc[j] - m); s += pr[j]; }
    const float inv = 1.0f / s;
    int i0 = 0; float b0 = pr[0];
    #pragma unroll
    for (int j = 1; j < NEXP; j++) if (pr[j] > b0) { b0 = pr[j]; i0 = j; }
    int i1 = -1; float b1 = -1.f;
    #pragma unroll
    for (int j = 0; j < NEXP; j++) if (j != i0 && pr[j] > b1) { b1 = pr[j]; i1 = j; }
    const int p0 = atomicAdd(&cnt[i0], 1);
    list[i0 * T_TOK + p0] = tok; wl[i0 * T_TOK + p0] = b0 * inv;
    const int p1 = atomicAdd(&cnt[i1], 1);
    list[i1 * T_TOK + p1] = tok; wl[i1 * T_TOK + p1] = b1 * inv;
  }
}

__global__ void scan_offs(const int* __restrict__ cnt, int* __restrict__ offs)
{
  if (blockIdx.x == 0 && threadIdx.x == 0) {
    int a = 0;
    for (int e = 0; e < NEXP; e++) { offs[e] = a; a += cnt[e]; }
    offs[NEXP] = a;
  }
}

// ---------------------------------------------------------------------------
// Routed FFN stage 1: h = silu(A@W1+B1) * (A@W3+B3); A gathered, h compacted.
// w1t/w3t are [e][H n][D k] (pre-transposed).
// ---------------------------------------------------------------------------
__launch_bounds__(256, 2)
__global__ void moe_ffn1(const ushort* __restrict__ embb, const ushort* __restrict__ xb,
                         const ushort* __restrict__ w1t, const ushort* __restrict__ w3t,
                         const float* __restrict__ B1, const float* __restrict__ B3,
                         const int* __restrict__ cnt, const int* __restrict__ offs,
                         const int* __restrict__ list, ushort* __restrict__ hb)
{
  const int e = blockIdx.z;
  const int ce = cnt[e];
  const int m0 = blockIdx.x * 128;
  if (m0 >= ce) return;
  const int n0 = blockIdx.y * 128;
  const int off = offs[e];
  const ushort* Ab = (e < NIN) ? xb : embb;

  __shared__ ushort As[128 * 32], Bs1[128 * 32], Bs3[128 * 32];

  const int tid = threadIdx.x;
  const int lane = tid & 63, w = tid >> 6;
  const int rr = w * 32 + (lane >> 2);      // staging row (and rr+16)
  const int kc = (lane & 3) * 8;            // 16B k-chunk within 32-k tile
  const int li = e * T_TOK;
  const ushort* ap0 = Ab + (size_t)list[li + min(m0 + rr,      ce - 1)] * DIM + kc;
  const ushort* ap1 = Ab + (size_t)list[li + min(m0 + rr + 16, ce - 1)] * DIM + kc;
  const ushort* W1e = w1t + (size_t)e * DIM * HID;
  const ushort* W3e = w3t + (size_t)e * DIM * HID;
  const ushort* bp0 = W1e + (size_t)(n0 + rr) * DIM + kc;
  const ushort* bp1 = W1e + (size_t)(n0 + rr + 16) * DIM + kc;
  const ushort* cp0 = W3e + (size_t)(n0 + rr) * DIM + kc;
  const ushort* cp1 = W3e + (size_t)(n0 + rr + 16) * DIM + kc;

  f4_t acc1[4][4], acc3[4][4];
  const f4_t fz = {0.f, 0.f, 0.f, 0.f};
  #pragma unroll
  for (int i = 0; i < 4; i++)
    #pragma unroll
    for (int j = 0; j < 4; j++) { acc1[i][j] = fz; acc3[i][j] = fz; }

  mfma_loop<DIM, true>(ap0, ap1, bp0, bp1, cp0, cp1, As, Bs1, Bs3, acc1, acc3, tid);

  const int wm = w & 1, wn = w >> 1;
  const int quad = lane >> 4, lr = lane & 15;
  #pragma unroll
  for (int mi = 0; mi < 4; mi++) {
    #pragma unroll
    for (int r = 0; r < 4; r++) {
      const int rowl = m0 + wm * 64 + mi * 16 + quad * 4 + r;
      if (rowl < ce) {
        ushort* hr = hb + (size_t)(off + rowl) * HID;
        #pragma unroll
        for (int ni = 0; ni < 4; ni++) {
          const int col = n0 + wn * 64 + ni * 16 + lr;
          const float v1 = acc1[mi][ni][r] + B1[e * HID + col];
          const float v3 = acc3[mi][ni][r] + B3[e * HID + col];
          const float sg = 1.0f / (1.0f + __expf(-v1));
          hr[col] = f2b(v1 * sg * v3);
        }
      }
    }
  }
}

// ---------------------------------------------------------------------------
// Routed FFN stage 2: y[tok] += w * (h_e @ W2 + B2). w2t is [e][D n][H k].
// ---------------------------------------------------------------------------
__launch_bounds__(256, 3)
__global__ void moe_ffn2(const ushort* __restrict__ hb, const ushort* __restrict__ w2t,
                         const float* __restrict__ B2,
                         const int* __restrict__ cnt, const int* __restrict__ offs,
                         const int* __restrict__ list, const float* __restrict__ wl,
                         float* __restrict__ y)
{
  const int e = blockIdx.z;
  const int ce = cnt[e];
  const int m0 = blockIdx.x * 128;
  if (m0 >= ce) return;
  const int n0 = blockIdx.y * 128;
  const int off = offs[e];

  __shared__ ushort As[128 * 32], Bs[128 * 32];

  const int tid = threadIdx.x;
  const int lane = tid & 63, w = tid >> 6;
  const int rr = w * 32 + (lane >> 2);
  const int kc = (lane & 3) * 8;
  const ushort* ap0 = hb + (size_t)(off + min(m0 + rr,      ce - 1)) * HID + kc;
  const ushort* ap1 = hb + (size_t)(off + min(m0 + rr + 16, ce - 1)) * HID + kc;
  const ushort* W2e = w2t + (size_t)e * HID * DIM;
  const ushort* bp0 = W2e + (size_t)(n0 + rr) * HID + kc;
  const ushort* bp1 = W2e + (size_t)(n0 + rr + 16) * HID + kc;

  f4_t acc[4][4];
  const f4_t fz = {0.f, 0.f, 0.f, 0.f};
  #pragma unroll
  for (int i = 0; i < 4; i++)
    #pragma unroll
    for (int j = 0; j < 4; j++) acc[i][j] = fz;

  mfma_loop<HID, false>(ap0, ap1, bp0, bp1, nullptr, nullptr, As, Bs, Bs, acc, acc, tid);

  const int wm = w & 1, wn = w >> 1;
  const int quad = lane >> 4, lr = lane & 15;
  #pragma unroll
  for (int mi = 0; mi < 4; mi++) {
    #pragma unroll
    for (int r = 0; r < 4; r++) {
      const int rowl = m0 + wm * 64 + mi * 16 + quad * 4 + r;
      if (rowl < ce) {
        const int tok = list[e * T_TOK + rowl];
        const float wgt = wl[e * T_TOK + rowl];
        float* yr = y + (size_t)tok * DIM;
        #pragma unroll
        for (int ni = 0; ni < 4; ni++) {
          const int col = n0 + wn * 64 + ni * 16 + lr;
          atomicAdd(&yr[col], wgt * (acc[mi][ni][r] + B2[e * DIM + col]));
        }
      }
    }
  }
}

// ---------------------------------------------------------------------------
// Shared expert stage 1: hs = silu(emb @ sW1 + sB1). sw1t is [HSH n][D k].
// ---------------------------------------------------------------------------
__launch_bounds__(256, 3)
__global__ void shared_ffn1(const ushort* __restrict__ embb, const ushort* __restrict__ sw1t,
                            const float* __restrict__ sB1, ushort* __restrict__ hsb)
{
  const int m0 = blockIdx.x * 128;
  const int n0 = blockIdx.y * 128;
  __shared__ ushort As[128 * 32], Bs[128 * 32];
  const int tid = threadIdx.x;
  const int lane = tid & 63, w = tid >> 6;
  const int rr = w * 32 + (lane >> 2);
  const int kc = (lane & 3) * 8;
  const ushort* ap0 = embb + (size_t)(m0 + rr) * DIM + kc;
  const ushort* ap1 = embb + (size_t)(m0 + rr + 16) * DIM + kc;
  const ushort* bp0 = sw1t + (size_t)(n0 + rr) * DIM + kc;
  const ushort* bp1 = sw1t + (size_t)(n0 + rr + 16) * DIM + kc;

  f4_t acc[4][4];
  const f4_t fz = {0.f, 0.f, 0.f, 0.f};
  #pragma unroll
  for (int i = 0; i < 4; i++)
    #pragma unroll
    for (int j = 0; j < 4; j++) acc[i][j] = fz;

  mfma_loop<DIM, false>(ap0, ap1, bp0, bp1, nullptr, nullptr, As, Bs, Bs, acc, acc, tid);

  const int wm = w & 1, wn = w >> 1;
  const int quad = lane >> 4, lr = lane & 15;
  #pragma unroll
  for (int mi = 0; mi < 4; mi++) {
    #pragma unroll
    for (int r = 0; r < 4; r++) {
      const int row = m0 + wm * 64 + mi * 16 + quad * 4 + r;
      ushort* hr = hsb + (size_t)row * HSH;
      #pragma unroll
      for (int ni = 0; ni < 4; ni++) {
        const int col = n0 + wn * 64 + ni * 16 + lr;
        const float v = acc[mi][ni][r] + sB1[col];
        const float sg = 1.0f / (1.0f + __expf(-v));
        hr[col] = f2b(v * sg);
      }
    }
  }
}

// ---------------------------------------------------------------------------
// Shared expert stage 2: y = hs @ sW2 + sB2 (initializes y). sw2t is [D n][HSH k].
// ---------------------------------------------------------------------------
__launch_bounds__(256, 3)
__global__ void shared_ffn2(const ushort* __restrict__ hsb, const ushort* __restrict__ sw2t,
                            const float* __restrict__ sB2, float* __restrict__ y)
{
  const int m0 = blockIdx.x * 128;
  const int n0 = blockIdx.y * 128;
  __shared__ ushort As[128 * 32], Bs[128 * 32];
  const int tid = threadIdx.x;
  const int lane = tid & 63, w = tid >> 6;
  const int rr = w * 32 + (lane >> 2);
  const int kc = (lane & 3) * 8;
  const ushort* ap0 = hsb + (size_t)(m0 + rr) * HSH + kc;
  const ushort* ap1 = hsb + (size_t)(m0 + rr + 16) * HSH + kc;
  const ushort* bp0 = sw2t + (size_t)(n0 + rr) * HSH + kc;
  const ushort* bp1 = sw2t + (size_t)(n0 + rr + 16) * HSH + kc;

  f4_t acc[4][4];
  const f4_t fz = {0.f, 0.f, 0.f, 0.f};
  #pragma unroll
  for (int i = 0; i < 4; i++)
    #pragma unroll
    for (int j = 0; j < 4; j++) acc[i][j] = fz;

  mfma_loop<HSH, false>(ap0, ap1, bp0, bp1, nullptr, nullptr, As, Bs, Bs, acc, acc, tid);

  const int wm = w & 1, wn = w >> 1;
  const int quad = lane >> 4, lr = lane & 15;
  #pragma unroll
  for (int mi = 0; mi < 4; mi++) {
    #pragma unroll
    for (int r = 0; r < 4; r++) {
      const int row = m0 + wm * 64 + mi * 16 + quad * 4 + r;
      float* yr = y + (size_t)row * DIM;
      #pragma unroll
      for (int ni = 0; ni < 4; ni++) {
        const int col = n0 + wn * 64 + ni * 16 + lr;
        yr[col] = acc[mi][ni][r] + sB2[col];
      }
    }
  }
}

// ---------------------------------------------------------------------------
// Launch
// ---------------------------------------------------------------------------
extern "C" void kernel_launch(void* const* d_in, const int* in_sizes, int n_in,
                              void* d_out, int out_size, void* d_ws, size_t ws_size,
                              hipStream_t stream)
{
  const float* emb = (const float*)d_in[0];
  const float* x   = (const float*)d_in[1];
  const float* gw  = (const float*)d_in[2];
  const float* W1  = (const float*)d_in[3];
  const float* B1  = (const float*)d_in[4];
  const float* W2  = (const float*)d_in[5];
  const float* B2  = (const float*)d_in[6];
  const float* W3  = (const float*)d_in[7];
  const float* B3  = (const float*)d_in[8];
  const float* sW1 = (const float*)d_in[9];
  const float* sB1 = (const float*)d_in[10];
  const float* sW2 = (const float*)d_in[11];
  const float* sB2 = (const float*)d_in[12];
  float* y = (float*)d_out;

  char* ws = (char*)d_ws;
  const size_t MB = 1024ULL * 1024ULL;
  ushort* emb_b = (ushort*)(ws + 0);        // [4096][1024]
  ushort* x_b   = (ushort*)(ws + 8 * MB);   // [4096][1024]
  ushort* w1t   = (ushort*)(ws + 16 * MB);  // [16][H][D]
  ushort* w3t   = (ushort*)(ws + 48 * MB);  // [16][H][D]
  ushort* w2t   = (ushort*)(ws + 80 * MB);  // [16][D][H]
  ushort* sw1t  = (ushort*)(ws + 112 * MB); // [HSH][D]
  ushort* sw2t  = (ushort*)(ws + 116 * MB); // [D][HSH]
  ushort* h_b   = (ushort*)(ws + 120 * MB); // [8192][1024] compact
  ushort* hs_b  = (ushort*)(ws + 136 * MB); // [4096][2048]
  int*   cnt    = (int*)(ws + 152 * MB);
  int*   offs   = cnt + 16;
  int*   list   = (int*)(ws + 152 * MB + 1024);
  float* wl     = (float*)(ws + 152 * MB + 1024 + 262144);

  hipMemsetAsync(cnt, 0, 64, stream);
  cast_ax<<<1024, 256, 0, stream>>>(emb, x, emb_b);
  transpose_cast<<<dim3(16, 16, NEXP), 256, 0, stream>>>(W1, w1t, DIM, HID);
  transpose_cast<<<dim3(16, 16, NEXP), 256, 0, stream>>>(W3, w3t, DIM, HID);
  transpose_cast<<<dim3(16, 16, NEXP), 256, 0, stream>>>(W2, w2t, HID, DIM);
  transpose_cast<<<dim3(32, 16, 1), 256, 0, stream>>>(sW1, sw1t, DIM, HSH);
  transpose_cast<<<dim3(16, 32, 1), 256, 0, stream>>>(sW2, sw2t, HSH, DIM);
  gate_topk<<<T_TOK, 256, 0, stream>>>(emb, gw, cnt, list, wl);
  scan_offs<<<1, 64, 0, stream>>>(cnt, offs);
  moe_ffn1<<<dim3(32, 8, NEXP), 256, 0, stream>>>(emb_b, x_b, w1t, w3t, B1, B3,
                                                  cnt, offs, list, h_b);
  shared_ffn1<<<dim3(32, 16), 256, 0, stream>>>(emb_b, sw1t, sB1, hs_b);
  shared_ffn2<<<dim3(32, 8), 256, 0, stream>>>(hs_b, sw2t, sB2, y);     // writes y
  moe_ffn2<<<dim3(32, 8, NEXP), 256, 0, stream>>>(h_b, w2t, B2,
                                                  cnt, offs, list, wl, y);  // += routed
}

// Round 3
// 1021.110 us; speedup vs baseline: 1.1045x; 1.0197x over previous
//
#include <hip/hip_runtime.h>

// Problem constants (fixed by the reference)
#define T_TOK 4096   // B*S tokens
#define DIM   1024   // model dim D
#define HID   1024   // expert hidden H
#define NEXP  16     // routed experts
#define HSH   2048   // shared hidden = NSH*H
#define NIN   2      // experts that consume x instead of emb

typedef __attribute__((ext_vector_type(8))) short bf8_t;  // 8 x bf16 (MFMA A/B frag)
typedef __attribute__((ext_vector_type(4))) float f4_t;   // 4 x f32  (MFMA C/D frag)

__device__ __forceinline__ ushort f2b(float f) {  // f32 -> bf16 RNE
  unsigned u = __float_as_uint(f);
  u = (u + 0x7FFFu + ((u >> 16) & 1u)) >> 16;
  return (ushort)u;
}

// ---------------------------------------------------------------------------
// Tile-packed (TP) layout: matrix [NR][NK] stored as 128x64 tiles, row-major
// tile grid (KT = NK/64 tiles per tile-row), 8192 elems (16KB) per tile,
// contiguous. Within a tile, element (r,c) sits at r*64 + swizzled column,
// where 8-elem chunks are XOR-swizzled by (r&7) so that MFMA fragment reads
// (16 rows x 16B per instruction) are LDS-bank-conflict-free despite the
// 128B (=32-bank) row stride. DMA copies tiles verbatim global->LDS.
// ---------------------------------------------------------------------------
__device__ __forceinline__ int tp_off(int r, int c) {
  return r * 64 + ((((c >> 3) ^ (r & 7)) << 3) | (c & 7));
}
__device__ __forceinline__ size_t tp_idx(int row, int col, int KT) {
  return ((size_t)((row >> 7) * KT + (col >> 6)) << 13) + tp_off(row & 127, col & 63);
}

// Async global->LDS DMA, 16B/lane; LDS dest is wave-uniform base + lane*16.
__device__ __forceinline__ void gl_lds16(const ushort* g, ushort* l) {
  __builtin_amdgcn_global_load_lds(
      (const __attribute__((address_space(1))) void*)g,
      (__attribute__((address_space(3))) void*)l, 16, 0, 0);
}

// ---------------------------------------------------------------------------
// TP MFMA K-loop: A tile-row at aT (advance 8192/tile), B at b1T (+b3T if
// DUAL), nkt tiles of K=64. Each wave DMA-stages a contiguous 4KB quarter of
// each 16KB tile (4x 1KB contiguous loads). 4 waves: 64x64 C-quadrants.
// ---------------------------------------------------------------------------
template<bool DUAL>
__device__ __forceinline__ void mfma_tp(
    const ushort* __restrict__ aT, const ushort* __restrict__ b1T,
    const ushort* __restrict__ b3T, int nkt,
    ushort* As, ushort* Bs1, ushort* Bs3,
    f4_t acc1[4][4], f4_t acc3[4][4], int tid)
{
  const int lane = tid & 63, w = tid >> 6;
  const int wm = w & 1, wn = w >> 1;
  const int quad = lane >> 4, lr = lane & 15;
  const int soff = w << 11;          // wave's 2048-elem quarter
  const int l8 = lane * 8;

  for (int kt = 0; kt < nkt; kt++) {
    const size_t tb = (size_t)kt << 13;
    const ushort* ga = aT + tb + soff + l8;
    const ushort* gb = b1T + tb + soff + l8;
    #pragma unroll
    for (int d = 0; d < 4; d++) {
      gl_lds16(ga + (d << 9), As  + soff + (d << 9));
      gl_lds16(gb + (d << 9), Bs1 + soff + (d << 9));
    }
    if (DUAL) {
      const ushort* gc = b3T + tb + soff + l8;
      #pragma unroll
      for (int d = 0; d < 4; d++)
        gl_lds16(gc + (d << 9), Bs3 + soff + (d << 9));
    }
    __syncthreads();
    #pragma unroll
    for (int half = 0; half < 2; half++) {
      const int ch = (half << 2) + quad;   // k-chunk index 0..7
      bf8_t af[4];
      #pragma unroll
      for (int mi = 0; mi < 4; mi++) {
        const int r = wm * 64 + mi * 16 + lr;
        af[mi] = *(const bf8_t*)&As[r * 64 + ((ch ^ (r & 7)) << 3)];
      }
      #pragma unroll
      for (int ni = 0; ni < 4; ni++) {
        const int n = wn * 64 + ni * 16 + lr;
        bf8_t b1 = *(const bf8_t*)&Bs1[n * 64 + ((ch ^ (n & 7)) << 3)];
        #pragma unroll
        for (int mi = 0; mi < 4; mi++)
          acc1[mi][ni] = __builtin_amdgcn_mfma_f32_16x16x32_bf16(af[mi], b1, acc1[mi][ni], 0, 0, 0);
        if (DUAL) {
          bf8_t b3 = *(const bf8_t*)&Bs3[n * 64 + ((ch ^ (n & 7)) << 3)];
          #pragma unroll
          for (int mi = 0; mi < 4; mi++)
            acc3[mi][ni] = __builtin_amdgcn_mfma_f32_16x16x32_bf16(af[mi], b3, acc3[mi][ni], 0, 0, 0);
        }
      }
    }
    __syncthreads();
  }
}

// ---------------------------------------------------------------------------
// Cast emb+x to bf16: flat [row][k] copies (for the gather) + TP emb (sffn1 A)
// ---------------------------------------------------------------------------
__global__ void cast_ax(const float* __restrict__ e_, const float* __restrict__ x_,
                        ushort* __restrict__ embf, ushort* __restrict__ xf,
                        ushort* __restrict__ etp)
{
  const int NC = (T_TOK * DIM) / 8;  // 524288 chunks per matrix
  const int stride = gridDim.x * blockDim.x;
  for (int c = blockIdx.x * blockDim.x + threadIdx.x; c < 2 * NC; c += stride) {
    const bool isE = c < NC;
    const int g = (isE ? c : c - NC) << 3;
    const float* src = isE ? e_ : x_;
    const float4 v0 = *(const float4*)(src + g);
    const float4 v1 = *(const float4*)(src + g + 4);
    ushort t[8];
    t[0] = f2b(v0.x); t[1] = f2b(v0.y); t[2] = f2b(v0.z); t[3] = f2b(v0.w);
    t[4] = f2b(v1.x); t[5] = f2b(v1.y); t[6] = f2b(v1.z); t[7] = f2b(v1.w);
    ushort* flat = isE ? embf : xf;
    *(uint4*)(flat + g) = *(uint4*)t;
    if (isE) {
      const int row = g >> 10, col = g & 1023;
      *(uint4*)&etp[tp_idx(row, col, 16)] = *(uint4*)t;
    }
  }
}

// ---------------------------------------------------------------------------
// Transpose + cast + TP-pack: src fp32 [z][R][C] -> logical [z][C][R] TP.
// ---------------------------------------------------------------------------
__global__ void transpose_cast_tp(const float* __restrict__ src, ushort* __restrict__ dst,
                                  int R, int C)
{
  __shared__ float t[64 * 65];
  const size_t mb = (size_t)blockIdx.z * R * C;
  const int r0 = blockIdx.y * 64, c0 = blockIdx.x * 64;
  const int tid = threadIdx.x;
  {
    const int row = tid >> 4;
    const int c4  = (tid & 15) * 4;
    #pragma unroll
    for (int p = 0; p < 4; p++) {
      const int r = p * 16 + row;
      const float4 v = *(const float4*)(src + mb + (size_t)(r0 + r) * C + c0 + c4);
      t[r * 65 + c4 + 0] = v.x; t[r * 65 + c4 + 1] = v.y;
      t[r * 65 + c4 + 2] = v.z; t[r * 65 + c4 + 3] = v.w;
    }
  }
  __syncthreads();
  {
    const int KT = R >> 6;
    const int oc  = tid >> 2;          // output row (N dim) = c0+oc
    const int seg = (tid & 3) * 16;    // k segment
    const int n = c0 + oc;
    ushort tmp[16];
    #pragma unroll
    for (int i = 0; i < 16; i++) tmp[i] = f2b(t[(seg + i) * 65 + oc]);
    *(uint4*)&dst[mb + tp_idx(n, r0 + seg, KT)]     = *(uint4*)&tmp[0];
    *(uint4*)&dst[mb + tp_idx(n, r0 + seg + 8, KT)] = *(uint4*)&tmp[8];
  }
}

// ---------------------------------------------------------------------------
// Gate: fp32 softmax(emb @ gate_w^T), top-2, per-expert compact lists
// ---------------------------------------------------------------------------
__global__ void gate_topk(const float* __restrict__ emb, const float* __restrict__ gw,
                          int* __restrict__ cnt, int* __restrict__ list, float* __restrict__ wl)
{
  __shared__ float se[DIM];
  __shared__ float sc[NEXP];
  const int tok = blockIdx.x;
  const int t = threadIdx.x;
  const float* row = emb + (size_t)tok * DIM;
  for (int i = t; i < DIM; i += 256) se[i] = row[i];
  __syncthreads();
  const int e = t >> 4, l = t & 15;
  float p = 0.f;
  const float* g = gw + e * DIM;
  for (int i = l; i < DIM; i += 16) p += se[i] * g[i];
  p += __shfl_xor(p, 1); p += __shfl_xor(p, 2);
  p += __shfl_xor(p, 4); p += __shfl_xor(p, 8);
  if (l == 0) sc[e] = p;
  __syncthreads();
  if (t == 0) {
    float m = sc[0];
    #pragma unroll
    for (int j = 1; j < NEXP; j++) m = fmaxf(m, sc[j]);
    float pr[NEXP]; float s = 0.f;
    #pragma unroll
    for (int j = 0; j < NEXP; j++) { pr[j] = expf(sc[j] - m); s += pr[j]; }
    const float inv = 1.0f / s;
    int i0 = 0; float b0 = pr[0];
    #pragma unroll
    for (int j = 1; j < NEXP; j++) if (pr[j] > b0) { b0 = pr[j]; i0 = j; }
    int i1 = -1; float b1 = -1.f;
    #pragma unroll
    for (int j = 0; j < NEXP; j++) if (j != i0 && pr[j] > b1) { b1 = pr[j]; i1 = j; }
    const int p0 = atomicAdd(&cnt[i0], 1);
    list[i0 * T_TOK + p0] = tok; wl[i0 * T_TOK + p0] = b0 * inv;
    const int p1 = atomicAdd(&cnt[i1], 1);
    list[i1 * T_TOK + p1] = tok; wl[i1 * T_TOK + p1] = b1 * inv;
  }
}

// offp[e] = 128-aligned prefix sum of counts (padded expert regions)
__global__ void scan_offs(const int* __restrict__ cnt, int* __restrict__ offp)
{
  if (blockIdx.x == 0 && threadIdx.x == 0) {
    int a = 0;
    for (int e = 0; e < NEXP; e++) { offp[e] = a; a += (cnt[e] + 127) & ~127; }
    offp[NEXP] = a;
  }
}

// ---------------------------------------------------------------------------
// Gather routed A rows into TP compact form (pad slots -> zeros)
// ---------------------------------------------------------------------------
__global__ void gather_a(const ushort* __restrict__ embf, const ushort* __restrict__ xf,
                         const int* __restrict__ cnt, const int* __restrict__ offp,
                         const int* __restrict__ list, ushort* __restrict__ ag)
{
  const int e = blockIdx.z;
  const int cpad = offp[e + 1] - offp[e];
  const int m0 = blockIdx.x * 128;
  if (m0 >= cpad) return;
  const int ce = cnt[e];
  const ushort* src = (e < NIN) ? xf : embf;
  const int tid = threadIdx.x;
  for (int rep = 0; rep < 64; rep++) {
    const int lin = rep * 256 + tid;     // 128 rows x 128 chunks
    const int r = lin >> 7, c8 = (lin & 127) << 3;
    const int s = m0 + r;
    uint4 v = make_uint4(0u, 0u, 0u, 0u);
    if (s < ce) {
      const int tok = list[e * T_TOK + s];
      v = *(const uint4*)&src[(size_t)tok * DIM + c8];
    }
    *(uint4*)&ag[tp_idx(offp[e] + s, c8, 16)] = v;
  }
}

// ---------------------------------------------------------------------------
// Stage 1 merged: z<16 -> routed SwiGLU front (h TP); z>=16 -> shared front (hs TP)
// ---------------------------------------------------------------------------
__launch_bounds__(256, 2)
__global__ void stage1(const ushort* __restrict__ ag, const ushort* __restrict__ etp,
                       const ushort* __restrict__ w1tp, const ushort* __restrict__ w3tp,
                       const ushort* __restrict__ sw1tp,
                       const float* __restrict__ B1, const float* __restrict__ B3,
                       const float* __restrict__ sB1,
                       const int* __restrict__ offp,
                       ushort* __restrict__ h_tp, ushort* __restrict__ hs_tp)
{
  __shared__ ushort As[8192], Bs1[8192], Bs3[8192];
  const int tid = threadIdx.x;
  const int lane = tid & 63, w = tid >> 6;
  const int wm = w & 1, wn = w >> 1;
  const int quad = lane >> 4, lr = lane & 15;
  const int z = blockIdx.z;

  f4_t acc1[4][4], acc3[4][4];
  const f4_t fz = {0.f, 0.f, 0.f, 0.f};
  #pragma unroll
  for (int i = 0; i < 4; i++)
    #pragma unroll
    for (int j = 0; j < 4; j++) { acc1[i][j] = fz; acc3[i][j] = fz; }

  if (z < NEXP) {
    const int e = z;
    const int cpad = offp[e + 1] - offp[e];
    const int m0 = blockIdx.x * 128;
    if (m0 >= cpad) return;
    const int n0 = blockIdx.y * 128;
    const ushort* aT  = ag + ((size_t)(((offp[e] + m0) >> 7) * 16) << 13);
    const ushort* b1T = w1tp + ((size_t)e << 20) + ((size_t)((n0 >> 7) * 16) << 13);
    const ushort* b3T = w3tp + ((size_t)e << 20) + ((size_t)((n0 >> 7) * 16) << 13);
    mfma_tp<true>(aT, b1T, b3T, 16, As, Bs1, Bs3, acc1, acc3, tid);
    #pragma unroll
    for (int mi = 0; mi < 4; mi++) {
      #pragma unroll
      for (int r = 0; r < 4; r++) {
        const int grow = offp[e] + m0 + wm * 64 + mi * 16 + quad * 4 + r;
        #pragma unroll
        for (int ni = 0; ni < 4; ni++) {
          const int col = n0 + wn * 64 + ni * 16 + lr;
          const float v1 = acc1[mi][ni][r] + B1[e * HID + col];
          const float v3 = acc3[mi][ni][r] + B3[e * HID + col];
          const float sg = 1.0f / (1.0f + __expf(-v1));
          h_tp[tp_idx(grow, col, 16)] = f2b(v1 * sg * v3);
        }
      }
    }
  } else {
    const int m0 = blockIdx.x * 128;
    const int nt = (z - NEXP) * 8 + blockIdx.y;
    const int n0 = nt * 128;
    const ushort* aT = etp + ((size_t)((m0 >> 7) * 16) << 13);
    const ushort* bT = sw1tp + ((size_t)((n0 >> 7) * 16) << 13);
    mfma_tp<false>(aT, bT, nullptr, 16, As, Bs1, Bs3, acc1, acc3, tid);
    #pragma unroll
    for (int mi = 0; mi < 4; mi++) {
      #pragma unroll
      for (int r = 0; r < 4; r++) {
        const int row = m0 + wm * 64 + mi * 16 + quad * 4 + r;
        #pragma unroll
        for (int ni = 0; ni < 4; ni++) {
          const int col = n0 + wn * 64 + ni * 16 + lr;
          const float v = acc1[mi][ni][r] + sB1[col];
          const float sg = 1.0f / (1.0f + __expf(-v));
          hs_tp[tp_idx(row, col, 32)] = f2b(v * sg);
        }
      }
    }
  }
}

// ---------------------------------------------------------------------------
// Stage 2 merged: z<16 -> routed back (atomic y += w*(h@W2+B2));
//                 z==16 -> shared back (atomic y += hs@sW2+sB2). y zero-inited.
// ---------------------------------------------------------------------------
__launch_bounds__(256, 3)
__global__ void stage2(const ushort* __restrict__ h_tp, const ushort* __restrict__ hs_tp,
                       const ushort* __restrict__ w2tp, const ushort* __restrict__ sw2tp,
                       const float* __restrict__ B2, const float* __restrict__ sB2,
                       const int* __restrict__ cnt, const int* __restrict__ offp,
                       const int* __restrict__ list, const float* __restrict__ wl,
                       float* __restrict__ y)
{
  __shared__ ushort As[8192], Bs[8192];
  const int tid = threadIdx.x;
  const int lane = tid & 63, w = tid >> 6;
  const int wm = w & 1, wn = w >> 1;
  const int quad = lane >> 4, lr = lane & 15;
  const int z = blockIdx.z;

  f4_t acc[4][4];
  const f4_t fz = {0.f, 0.f, 0.f, 0.f};
  #pragma unroll
  for (int i = 0; i < 4; i++)
    #pragma unroll
    for (int j = 0; j < 4; j++) acc[i][j] = fz;

  if (z < NEXP) {
    const int e = z;
    const int cpad = offp[e + 1] - offp[e];
    const int m0 = blockIdx.x * 128;
    if (m0 >= cpad) return;
    const int ce = cnt[e];
    const int n0 = blockIdx.y * 128;
    const ushort* aT = h_tp + ((size_t)(((offp[e] + m0) >> 7) * 16) << 13);
    const ushort* bT = w2tp + ((size_t)e << 20) + ((size_t)((n0 >> 7) * 16) << 13);
    mfma_tp<false>(aT, bT, nullptr, 16, As, Bs, Bs, acc, acc, tid);
    #pragma unroll
    for (int mi = 0; mi < 4; mi++) {
      #pragma unroll
      for (int r = 0; r < 4; r++) {
        const int rowl = m0 + wm * 64 + mi * 16 + quad * 4 + r;
        if (rowl < ce) {
          const int tok = list[e * T_TOK + rowl];
          const float wgt = wl[e * T_TOK + rowl];
          float* yr = y + (size_t)tok * DIM;
          #pragma unroll
          for (int ni = 0; ni < 4; ni++) {
            const int col = n0 + wn * 64 + ni * 16 + lr;
            atomicAdd(&yr[col], wgt * (acc[mi][ni][r] + B2[e * DIM + col]));
          }
        }
      }
    }
  } else {
    const int m0 = blockIdx.x * 128;
    const int n0 = blockIdx.y * 128;
    const ushort* aT = hs_tp + ((size_t)((m0 >> 7) * 32) << 13);
    const ushort* bT = sw2tp + ((size_t)((n0 >> 7) * 32) << 13);
    mfma_tp<false>(aT, bT, nullptr, 32, As, Bs, Bs, acc, acc, tid);
    #pragma unroll
    for (int mi = 0; mi < 4; mi++) {
      #pragma unroll
      for (int r = 0; r < 4; r++) {
        const int row = m0 + wm * 64 + mi * 16 + quad * 4 + r;
        float* yr = y + (size_t)row * DIM;
        #pragma unroll
        for (int ni = 0; ni < 4; ni++) {
          const int col = n0 + wn * 64 + ni * 16 + lr;
          atomicAdd(&yr[col], acc[mi][ni][r] + sB2[col]);
        }
      }
    }
  }
}

// ---------------------------------------------------------------------------
// Launch
// ---------------------------------------------------------------------------
extern "C" void kernel_launch(void* const* d_in, const int* in_sizes, int n_in,
                              void* d_out, int out_size, void* d_ws, size_t ws_size,
                              hipStream_t stream)
{
  const float* emb = (const float*)d_in[0];
  const float* x   = (const float*)d_in[1];
  const float* gw  = (const float*)d_in[2];
  const float* W1  = (const float*)d_in[3];
  const float* B1  = (const float*)d_in[4];
  const float* W2  = (const float*)d_in[5];
  const float* B2  = (const float*)d_in[6];
  const float* W3  = (const float*)d_in[7];
  const float* B3  = (const float*)d_in[8];
  const float* sW1 = (const float*)d_in[9];
  const float* sB1 = (const float*)d_in[10];
  const float* sW2 = (const float*)d_in[11];
  const float* sB2 = (const float*)d_in[12];
  float* y = (float*)d_out;

  char* ws = (char*)d_ws;
  const size_t MB = 1024ULL * 1024ULL;
  ushort* embf  = (ushort*)(ws + 0);        // [4096][1024] flat
  ushort* xf    = (ushort*)(ws + 8 * MB);   // [4096][1024] flat
  ushort* etp   = (ushort*)(ws + 16 * MB);  // emb TP (KT=16)
  ushort* w1tp  = (ushort*)(ws + 24 * MB);  // [16] x TP [1024n][1024k]
  ushort* w3tp  = (ushort*)(ws + 56 * MB);
  ushort* w2tp  = (ushort*)(ws + 88 * MB);  // [16] x TP [1024n][1024k]
  ushort* sw1tp = (ushort*)(ws + 120 * MB); // TP [2048n][1024k]
  ushort* sw2tp = (ushort*)(ws + 124 * MB); // TP [1024n][2048k]
  ushort* ag    = (ushort*)(ws + 128 * MB); // gathered A, TP, <=10240 rows
  ushort* h_tp  = (ushort*)(ws + 148 * MB); // routed hidden, TP, <=10240 rows
  ushort* hs_tp = (ushort*)(ws + 168 * MB); // shared hidden, TP [4096][2048]
  int*   cnt    = (int*)(ws + 184 * MB);
  int*   offp   = cnt + 16;                 // [17]
  int*   list   = (int*)(ws + 184 * MB + 1024);
  float* wl     = (float*)(ws + 184 * MB + 1024 + 262144);

  hipMemsetAsync(cnt, 0, 64, stream);
  hipMemsetAsync(y, 0, (size_t)T_TOK * DIM * sizeof(float), stream);
  cast_ax<<<1024, 256, 0, stream>>>(emb, x, embf, xf, etp);
  transpose_cast_tp<<<dim3(16, 16, NEXP), 256, 0, stream>>>(W1, w1tp, DIM, HID);
  transpose_cast_tp<<<dim3(16, 16, NEXP), 256, 0, stream>>>(W3, w3tp, DIM, HID);
  transpose_cast_tp<<<dim3(16, 16, NEXP), 256, 0, stream>>>(W2, w2tp, HID, DIM);
  transpose_cast_tp<<<dim3(32, 16, 1), 256, 0, stream>>>(sW1, sw1tp, DIM, HSH);
  transpose_cast_tp<<<dim3(16, 32, 1), 256, 0, stream>>>(sW2, sw2tp, HSH, DIM);
  gate_topk<<<T_TOK, 256, 0, stream>>>(emb, gw, cnt, list, wl);
  scan_offs<<<1, 64, 0, stream>>>(cnt, offp);
  gather_a<<<dim3(32, 1, NEXP), 256, 0, stream>>>(embf, xf, cnt, offp, list, ag);
  stage1<<<dim3(32, 8, 18), 256, 0, stream>>>(ag, etp, w1tp, w3tp, sw1tp,
                                              B1, B3, sB1, offp, h_tp, hs_tp);
  stage2<<<dim3(32, 8, 17), 256, 0, stream>>>(h_tp, hs_tp, w2tp, sw2tp, B2, sB2,
                                              cnt, offp, list, wl, y);
}

// Round 4
// 654.214 us; speedup vs baseline: 1.7240x; 1.5608x over previous
//
#include <hip/hip_runtime.h>

// Problem constants (fixed by the reference)
#define T_TOK 4096   // B*S tokens
#define DIM   1024   // model dim D
#define HID   1024   // expert hidden H
#define NEXP  16     // routed experts
#define HSH   2048   // shared hidden = NSH*H
#define NIN   2      // experts that consume x instead of emb
#define MT_MAX 80    // max routed m-tiles: (8192 + 16*127)/128 rounded up

typedef __attribute__((ext_vector_type(8))) short bf8_t;  // 8 x bf16 (MFMA A/B frag)
typedef __attribute__((ext_vector_type(4))) float f4_t;   // 4 x f32  (MFMA C/D frag)

__device__ __forceinline__ ushort f2b(float f) {  // f32 -> bf16 RNE
  unsigned u = __float_as_uint(f);
  u = (u + 0x7FFFu + ((u >> 16) & 1u)) >> 16;
  return (ushort)u;
}

// ---------------------------------------------------------------------------
// Tile-packed (TP) layout: matrix [NR][NK] stored as 128x64 tiles, row-major
// tile grid (KT = NK/64 tiles per tile-row), 8192 elems (16KB) per tile,
// contiguous. Element (r,c) at r*64 + XOR-swizzled column (by r&7) so MFMA
// fragment ds_read_b128 are bank-conflict-free. DMA copies tiles verbatim.
// ---------------------------------------------------------------------------
__device__ __forceinline__ int tp_off(int r, int c) {
  return r * 64 + ((((c >> 3) ^ (r & 7)) << 3) | (c & 7));
}
__device__ __forceinline__ size_t tp_idx(int row, int col, int KT) {
  return ((size_t)((row >> 7) * KT + (col >> 6)) << 13) + tp_off(row & 127, col & 63);
}

// Async global->LDS DMA, 16B/lane; LDS dest is wave-uniform base + lane*16.
__device__ __forceinline__ void gl_lds16(const ushort* g, ushort* l) {
  __builtin_amdgcn_global_load_lds(
      (const __attribute__((address_space(1))) void*)g,
      (__attribute__((address_space(3))) void*)l, 16, 0, 0);
}

// ---------------------------------------------------------------------------
// TP MFMA K-loop: nkt tiles of K=64. Each wave DMA-stages a contiguous 4KB
// quarter of each 16KB tile. 4 waves: 64x64 C-quadrants via 16x16x32 MFMA.
// ---------------------------------------------------------------------------
template<bool DUAL>
__device__ __forceinline__ void mfma_tp(
    const ushort* __restrict__ aT, const ushort* __restrict__ b1T,
    const ushort* __restrict__ b3T, int nkt,
    ushort* As, ushort* Bs1, ushort* Bs3,
    f4_t acc1[4][4], f4_t acc3[4][4], int tid)
{
  const int lane = tid & 63, w = tid >> 6;
  const int wm = w & 1, wn = w >> 1;
  const int quad = lane >> 4, lr = lane & 15;
  const int soff = w << 11;          // wave's 2048-elem quarter
  const int l8 = lane * 8;

  for (int kt = 0; kt < nkt; kt++) {
    const size_t tb = (size_t)kt << 13;
    const ushort* ga = aT + tb + soff + l8;
    const ushort* gb = b1T + tb + soff + l8;
    #pragma unroll
    for (int d = 0; d < 4; d++) {
      gl_lds16(ga + (d << 9), As  + soff + (d << 9));
      gl_lds16(gb + (d << 9), Bs1 + soff + (d << 9));
    }
    if (DUAL) {
      const ushort* gc = b3T + tb + soff + l8;
      #pragma unroll
      for (int d = 0; d < 4; d++)
        gl_lds16(gc + (d << 9), Bs3 + soff + (d << 9));
    }
    __syncthreads();
    #pragma unroll
    for (int half = 0; half < 2; half++) {
      const int ch = (half << 2) + quad;   // k-chunk index 0..7
      bf8_t af[4];
      #pragma unroll
      for (int mi = 0; mi < 4; mi++) {
        const int r = wm * 64 + mi * 16 + lr;
        af[mi] = *(const bf8_t*)&As[r * 64 + ((ch ^ (r & 7)) << 3)];
      }
      #pragma unroll
      for (int ni = 0; ni < 4; ni++) {
        const int n = wn * 64 + ni * 16 + lr;
        bf8_t b1 = *(const bf8_t*)&Bs1[n * 64 + ((ch ^ (n & 7)) << 3)];
        #pragma unroll
        for (int mi = 0; mi < 4; mi++)
          acc1[mi][ni] = __builtin_amdgcn_mfma_f32_16x16x32_bf16(af[mi], b1, acc1[mi][ni], 0, 0, 0);
        if (DUAL) {
          bf8_t b3 = *(const bf8_t*)&Bs3[n * 64 + ((ch ^ (n & 7)) << 3)];
          #pragma unroll
          for (int mi = 0; mi < 4; mi++)
            acc3[mi][ni] = __builtin_amdgcn_mfma_f32_16x16x32_bf16(af[mi], b3, acc3[mi][ni], 0, 0, 0);
        }
      }
    }
    __syncthreads();
  }
}

// ---------------------------------------------------------------------------
// Cast emb+x to bf16: flat [row][k] copies (for the gather) + TP emb
// ---------------------------------------------------------------------------
__global__ void cast_ax(const float* __restrict__ e_, const float* __restrict__ x_,
                        ushort* __restrict__ embf, ushort* __restrict__ xf,
                        ushort* __restrict__ etp)
{
  const int NC = (T_TOK * DIM) / 8;
  const int stride = gridDim.x * blockDim.x;
  for (int c = blockIdx.x * blockDim.x + threadIdx.x; c < 2 * NC; c += stride) {
    const bool isE = c < NC;
    const int g = (isE ? c : c - NC) << 3;
    const float* src = isE ? e_ : x_;
    const float4 v0 = *(const float4*)(src + g);
    const float4 v1 = *(const float4*)(src + g + 4);
    ushort t[8];
    t[0] = f2b(v0.x); t[1] = f2b(v0.y); t[2] = f2b(v0.z); t[3] = f2b(v0.w);
    t[4] = f2b(v1.x); t[5] = f2b(v1.y); t[6] = f2b(v1.z); t[7] = f2b(v1.w);
    ushort* flat = isE ? embf : xf;
    *(uint4*)(flat + g) = *(uint4*)t;
    if (isE) {
      const int row = g >> 10, col = g & 1023;
      *(uint4*)&etp[tp_idx(row, col, 16)] = *(uint4*)t;
    }
  }
}

// ---------------------------------------------------------------------------
// Transpose + cast + TP-pack: src fp32 [z][R][C] -> logical [z][C][R] TP.
// ---------------------------------------------------------------------------
__global__ void transpose_cast_tp(const float* __restrict__ src, ushort* __restrict__ dst,
                                  int R, int C)
{
  __shared__ float t[64 * 65];
  const size_t mb = (size_t)blockIdx.z * R * C;
  const int r0 = blockIdx.y * 64, c0 = blockIdx.x * 64;
  const int tid = threadIdx.x;
  {
    const int row = tid >> 4;
    const int c4  = (tid & 15) * 4;
    #pragma unroll
    for (int p = 0; p < 4; p++) {
      const int r = p * 16 + row;
      const float4 v = *(const float4*)(src + mb + (size_t)(r0 + r) * C + c0 + c4);
      t[r * 65 + c4 + 0] = v.x; t[r * 65 + c4 + 1] = v.y;
      t[r * 65 + c4 + 2] = v.z; t[r * 65 + c4 + 3] = v.w;
    }
  }
  __syncthreads();
  {
    const int KT = R >> 6;
    const int oc  = tid >> 2;
    const int seg = (tid & 3) * 16;
    const int n = c0 + oc;
    ushort tmp[16];
    #pragma unroll
    for (int i = 0; i < 16; i++) tmp[i] = f2b(t[(seg + i) * 65 + oc]);
    *(uint4*)&dst[mb + tp_idx(n, r0 + seg, KT)]     = *(uint4*)&tmp[0];
    *(uint4*)&dst[mb + tp_idx(n, r0 + seg + 8, KT)] = *(uint4*)&tmp[8];
  }
}

// ---------------------------------------------------------------------------
// Gate: fp32 softmax(emb @ gate_w^T), top-2, per-expert compact lists
// ---------------------------------------------------------------------------
__global__ void gate_topk(const float* __restrict__ emb, const float* __restrict__ gw,
                          int* __restrict__ cnt, int* __restrict__ list, float* __restrict__ wl)
{
  __shared__ float se[DIM];
  __shared__ float sc[NEXP];
  const int tok = blockIdx.x;
  const int t = threadIdx.x;
  const float* row = emb + (size_t)tok * DIM;
  for (int i = t; i < DIM; i += 256) se[i] = row[i];
  __syncthreads();
  const int e = t >> 4, l = t & 15;
  float p = 0.f;
  const float* g = gw + e * DIM;
  for (int i = l; i < DIM; i += 16) p += se[i] * g[i];
  p += __shfl_xor(p, 1); p += __shfl_xor(p, 2);
  p += __shfl_xor(p, 4); p += __shfl_xor(p, 8);
  if (l == 0) sc[e] = p;
  __syncthreads();
  if (t == 0) {
    float m = sc[0];
    #pragma unroll
    for (int j = 1; j < NEXP; j++) m = fmaxf(m, sc[j]);
    float pr[NEXP]; float s = 0.f;
    #pragma unroll
    for (int j = 0; j < NEXP; j++) { pr[j] = expf(sc[j] - m); s += pr[j]; }
    const float inv = 1.0f / s;
    int i0 = 0; float b0 = pr[0];
    #pragma unroll
    for (int j = 1; j < NEXP; j++) if (pr[j] > b0) { b0 = pr[j]; i0 = j; }
    int i1 = -1; float b1 = -1.f;
    #pragma unroll
    for (int j = 0; j < NEXP; j++) if (j != i0 && pr[j] > b1) { b1 = pr[j]; i1 = j; }
    const int p0 = atomicAdd(&cnt[i0], 1);
    list[i0 * T_TOK + p0] = tok; wl[i0 * T_TOK + p0] = b0 * inv;
    const int p1 = atomicAdd(&cnt[i1], 1);
    list[i1 * T_TOK + p1] = tok; wl[i1 * T_TOK + p1] = b1 * inv;
  }
}

// offp[e] = 128-aligned prefix sum; offp[17] = #m-tiles; tbl[2*mt] = {e, row0}
__global__ void scan_offs(const int* __restrict__ cnt, int* __restrict__ offp,
                          int* __restrict__ tbl)
{
  if (blockIdx.x == 0 && threadIdx.x == 0) {
    int a = 0, nm = 0;
    for (int e = 0; e < NEXP; e++) {
      offp[e] = a;
      const int c = (cnt[e] + 127) & ~127;
      for (int r = 0; r < c; r += 128) { tbl[2 * nm] = e; tbl[2 * nm + 1] = a + r; nm++; }
      a += c;
    }
    offp[NEXP] = a;
    offp[NEXP + 1] = nm;
  }
}

// ---------------------------------------------------------------------------
// Gather routed A rows into TP compact form (pad slots -> zeros). Flat grid:
// one block per real m-tile (table-driven).
// ---------------------------------------------------------------------------
__global__ void gather_a(const ushort* __restrict__ embf, const ushort* __restrict__ xf,
                         const int* __restrict__ cnt, const int* __restrict__ offp,
                         const int* __restrict__ tbl, const int* __restrict__ list,
                         ushort* __restrict__ ag)
{
  const int mt = blockIdx.x;
  if (mt >= offp[NEXP + 1]) return;
  const int e = tbl[2 * mt], row0 = tbl[2 * mt + 1];
  const int ce = cnt[e];
  const int s0 = row0 - offp[e];
  const ushort* src = (e < NIN) ? xf : embf;
  const int tid = threadIdx.x;
  for (int rep = 0; rep < 64; rep++) {
    const int lin = rep * 256 + tid;
    const int r = lin >> 7, c8 = (lin & 127) << 3;
    const int s = s0 + r;
    uint4 v = make_uint4(0u, 0u, 0u, 0u);
    if (s < ce) {
      const int tok = list[e * T_TOK + s];
      v = *(const uint4*)&src[(size_t)tok * DIM + c8];
    }
    *(uint4*)&ag[tp_idx(row0 + r, c8, 16)] = v;
  }
}

// ---------------------------------------------------------------------------
// Stage 1, flat grid: b < 512 -> shared front (hs TP); else routed SwiGLU
// front (h TP), table-driven m-tiles (tiny early-exit tail at the very end).
// ---------------------------------------------------------------------------
__launch_bounds__(256, 2)
__global__ void stage1(const ushort* __restrict__ ag, const ushort* __restrict__ etp,
                       const ushort* __restrict__ w1tp, const ushort* __restrict__ w3tp,
                       const ushort* __restrict__ sw1tp,
                       const float* __restrict__ B1, const float* __restrict__ B3,
                       const float* __restrict__ sB1,
                       const int* __restrict__ offp, const int* __restrict__ tbl,
                       ushort* __restrict__ h_tp, ushort* __restrict__ hs_tp)
{
  __shared__ ushort As[8192], Bs1[8192], Bs3[8192];
  const int tid = threadIdx.x;
  const int lane = tid & 63, w = tid >> 6;
  const int wm = w & 1, wn = w >> 1;
  const int quad = lane >> 4, lr = lane & 15;
  const int b = blockIdx.x;

  f4_t acc1[4][4], acc3[4][4];
  const f4_t fz = {0.f, 0.f, 0.f, 0.f};
  #pragma unroll
  for (int i = 0; i < 4; i++)
    #pragma unroll
    for (int j = 0; j < 4; j++) { acc1[i][j] = fz; acc3[i][j] = fz; }

  if (b < 512) {                       // ---- shared expert front: all real
    const int m0 = (b >> 4) << 7;
    const int n0 = (b & 15) << 7;
    const ushort* aT = etp + ((size_t)((m0 >> 7) * 16) << 13);
    const ushort* bT = sw1tp + ((size_t)((n0 >> 7) * 16) << 13);
    mfma_tp<false>(aT, bT, nullptr, 16, As, Bs1, Bs3, acc1, acc3, tid);
    #pragma unroll
    for (int mi = 0; mi < 4; mi++) {
      #pragma unroll
      for (int r = 0; r < 4; r++) {
        const int row = m0 + wm * 64 + mi * 16 + quad * 4 + r;
        #pragma unroll
        for (int ni = 0; ni < 4; ni++) {
          const int col = n0 + wn * 64 + ni * 16 + lr;
          const float v = acc1[mi][ni][r] + sB1[col];
          const float sg = 1.0f / (1.0f + __expf(-v));
          hs_tp[tp_idx(row, col, 32)] = f2b(v * sg);
        }
      }
    }
  } else {                             // ---- routed SwiGLU front
    const int t = b - 512;
    const int mt = t >> 3;
    if (mt >= offp[NEXP + 1]) return;
    const int n0 = (t & 7) << 7;
    const int e = tbl[2 * mt], row0 = tbl[2 * mt + 1];
    const ushort* aT  = ag + ((size_t)((row0 >> 7) * 16) << 13);
    const ushort* b1T = w1tp + ((size_t)e << 20) + ((size_t)((n0 >> 7) * 16) << 13);
    const ushort* b3T = w3tp + ((size_t)e << 20) + ((size_t)((n0 >> 7) * 16) << 13);
    mfma_tp<true>(aT, b1T, b3T, 16, As, Bs1, Bs3, acc1, acc3, tid);
    #pragma unroll
    for (int mi = 0; mi < 4; mi++) {
      #pragma unroll
      for (int r = 0; r < 4; r++) {
        const int grow = row0 + wm * 64 + mi * 16 + quad * 4 + r;
        #pragma unroll
        for (int ni = 0; ni < 4; ni++) {
          const int col = n0 + wn * 64 + ni * 16 + lr;
          const float v1 = acc1[mi][ni][r] + B1[e * HID + col];
          const float v3 = acc3[mi][ni][r] + B3[e * HID + col];
          const float sg = 1.0f / (1.0f + __expf(-v1));
          h_tp[tp_idx(grow, col, 16)] = f2b(v1 * sg * v3);
        }
      }
    }
  }
}

// ---------------------------------------------------------------------------
// Stage 2, flat grid: b < 256 -> shared back; else routed back (table-driven).
// Both atomicAdd into zero-inited y.
// ---------------------------------------------------------------------------
__launch_bounds__(256, 3)
__global__ void stage2(const ushort* __restrict__ h_tp, const ushort* __restrict__ hs_tp,
                       const ushort* __restrict__ w2tp, const ushort* __restrict__ sw2tp,
                       const float* __restrict__ B2, const float* __restrict__ sB2,
                       const int* __restrict__ cnt, const int* __restrict__ offp,
                       const int* __restrict__ tbl, const int* __restrict__ list,
                       const float* __restrict__ wl, float* __restrict__ y)
{
  __shared__ ushort As[8192], Bs[8192];
  const int tid = threadIdx.x;
  const int lane = tid & 63, w = tid >> 6;
  const int wm = w & 1, wn = w >> 1;
  const int quad = lane >> 4, lr = lane & 15;
  const int b = blockIdx.x;

  f4_t acc[4][4];
  const f4_t fz = {0.f, 0.f, 0.f, 0.f};
  #pragma unroll
  for (int i = 0; i < 4; i++)
    #pragma unroll
    for (int j = 0; j < 4; j++) acc[i][j] = fz;

  if (b < 256) {                       // ---- shared expert back (K=2048)
    const int m0 = (b >> 3) << 7;
    const int n0 = (b & 7) << 7;
    const ushort* aT = hs_tp + ((size_t)((m0 >> 7) * 32) << 13);
    const ushort* bT = sw2tp + ((size_t)((n0 >> 7) * 32) << 13);
    mfma_tp<false>(aT, bT, nullptr, 32, As, Bs, Bs, acc, acc, tid);
    #pragma unroll
    for (int mi = 0; mi < 4; mi++) {
      #pragma unroll
      for (int r = 0; r < 4; r++) {
        const int row = m0 + wm * 64 + mi * 16 + quad * 4 + r;
        float* yr = y + (size_t)row * DIM;
        #pragma unroll
        for (int ni = 0; ni < 4; ni++) {
          const int col = n0 + wn * 64 + ni * 16 + lr;
          atomicAdd(&yr[col], acc[mi][ni][r] + sB2[col]);
        }
      }
    }
  } else {                             // ---- routed back (K=1024)
    const int t = b - 256;
    const int mt = t >> 3;
    if (mt >= offp[NEXP + 1]) return;
    const int n0 = (t & 7) << 7;
    const int e = tbl[2 * mt], row0 = tbl[2 * mt + 1];
    const int ce = cnt[e];
    const int s0 = row0 - offp[e];
    const ushort* aT = h_tp + ((size_t)((row0 >> 7) * 16) << 13);
    const ushort* bT = w2tp + ((size_t)e << 20) + ((size_t)((n0 >> 7) * 16) << 13);
    mfma_tp<false>(aT, bT, nullptr, 16, As, Bs, Bs, acc, acc, tid);
    #pragma unroll
    for (int mi = 0; mi < 4; mi++) {
      #pragma unroll
      for (int r = 0; r < 4; r++) {
        const int rowl = s0 + wm * 64 + mi * 16 + quad * 4 + r;
        if (rowl < ce) {
          const int tok = list[e * T_TOK + rowl];
          const float wgt = wl[e * T_TOK + rowl];
          float* yr = y + (size_t)tok * DIM;
          #pragma unroll
          for (int ni = 0; ni < 4; ni++) {
            const int col = n0 + wn * 64 + ni * 16 + lr;
            atomicAdd(&yr[col], wgt * (acc[mi][ni][r] + B2[e * DIM + col]));
          }
        }
      }
    }
  }
}

// ---------------------------------------------------------------------------
// Launch
// ---------------------------------------------------------------------------
extern "C" void kernel_launch(void* const* d_in, const int* in_sizes, int n_in,
                              void* d_out, int out_size, void* d_ws, size_t ws_size,
                              hipStream_t stream)
{
  const float* emb = (const float*)d_in[0];
  const float* x   = (const float*)d_in[1];
  const float* gw  = (const float*)d_in[2];
  const float* W1  = (const float*)d_in[3];
  const float* B1  = (const float*)d_in[4];
  const float* W2  = (const float*)d_in[5];
  const float* B2  = (const float*)d_in[6];
  const float* W3  = (const float*)d_in[7];
  const float* B3  = (const float*)d_in[8];
  const float* sW1 = (const float*)d_in[9];
  const float* sB1 = (const float*)d_in[10];
  const float* sW2 = (const float*)d_in[11];
  const float* sB2 = (const float*)d_in[12];
  float* y = (float*)d_out;

  char* ws = (char*)d_ws;
  const size_t MB = 1024ULL * 1024ULL;
  ushort* embf  = (ushort*)(ws + 0);        // [4096][1024] flat
  ushort* xf    = (ushort*)(ws + 8 * MB);   // [4096][1024] flat
  ushort* etp   = (ushort*)(ws + 16 * MB);  // emb TP (KT=16)
  ushort* w1tp  = (ushort*)(ws + 24 * MB);  // [16] x TP [1024n][1024k]
  ushort* w3tp  = (ushort*)(ws + 56 * MB);
  ushort* w2tp  = (ushort*)(ws + 88 * MB);  // [16] x TP [1024n][1024k]
  ushort* sw1tp = (ushort*)(ws + 120 * MB); // TP [2048n][1024k]
  ushort* sw2tp = (ushort*)(ws + 124 * MB); // TP [1024n][2048k]
  ushort* ag    = (ushort*)(ws + 128 * MB); // gathered A, TP, <=10240 rows
  ushort* h_tp  = (ushort*)(ws + 148 * MB); // routed hidden, TP, <=10240 rows
  ushort* hs_tp = (ushort*)(ws + 168 * MB); // shared hidden, TP [4096][2048]
  int*   cnt    = (int*)(ws + 184 * MB);    // [16]
  int*   offp   = cnt + 16;                 // [18]  (offp[17] = #m-tiles)
  int*   tbl    = offp + 18;                // [2*MT_MAX]
  int*   list   = (int*)(ws + 184 * MB + 1024);
  float* wl     = (float*)(ws + 184 * MB + 1024 + 262144);

  hipMemsetAsync(cnt, 0, 64, stream);
  hipMemsetAsync(y, 0, (size_t)T_TOK * DIM * sizeof(float), stream);
  cast_ax<<<1024, 256, 0, stream>>>(emb, x, embf, xf, etp);
  transpose_cast_tp<<<dim3(16, 16, NEXP), 256, 0, stream>>>(W1, w1tp, DIM, HID);
  transpose_cast_tp<<<dim3(16, 16, NEXP), 256, 0, stream>>>(W3, w3tp, DIM, HID);
  transpose_cast_tp<<<dim3(16, 16, NEXP), 256, 0, stream>>>(W2, w2tp, HID, DIM);
  transpose_cast_tp<<<dim3(32, 16, 1), 256, 0, stream>>>(sW1, sw1tp, DIM, HSH);
  transpose_cast_tp<<<dim3(16, 32, 1), 256, 0, stream>>>(sW2, sw2tp, HSH, DIM);
  gate_topk<<<T_TOK, 256, 0, stream>>>(emb, gw, cnt, list, wl);
  scan_offs<<<1, 64, 0, stream>>>(cnt, offp, tbl);
  gather_a<<<MT_MAX, 256, 0, stream>>>(embf, xf, cnt, offp, tbl, list, ag);
  stage1<<<512 + MT_MAX * 8, 256, 0, stream>>>(ag, etp, w1tp, w3tp, sw1tp,
                                               B1, B3, sB1, offp, tbl, h_tp, hs_tp);
  stage2<<<256 + MT_MAX * 8, 256, 0, stream>>>(h_tp, hs_tp, w2tp, sw2tp, B2, sB2,
                                               cnt, offp, tbl, list, wl, y);
}

// Round 5
// 636.314 us; speedup vs baseline: 1.7725x; 1.0281x over previous
//
#include <hip/hip_runtime.h>

// Problem constants (fixed by the reference)
#define T_TOK 4096   // B*S tokens
#define DIM   1024   // model dim D
#define HID   1024   // expert hidden H
#define NEXP  16     // routed experts
#define HSH   2048   // shared hidden = NSH*H
#define NIN   2      // experts that consume x instead of emb
#define MT_MAX 80    // max routed m-tiles: (8192 + 16*127)/128 rounded up

typedef __attribute__((ext_vector_type(8))) short bf8_t;  // 8 x bf16 (MFMA A/B frag)
typedef __attribute__((ext_vector_type(4))) float f4_t;   // 4 x f32  (MFMA C/D frag)

__device__ __forceinline__ ushort f2b(float f) {  // f32 -> bf16 RNE
  unsigned u = __float_as_uint(f);
  u = (u + 0x7FFFu + ((u >> 16) & 1u)) >> 16;
  return (ushort)u;
}

// ---------------------------------------------------------------------------
// Tile-packed (TP) layout: matrix [NR][NK] stored as 128x64 tiles, row-major
// tile grid (KT = NK/64 tiles per tile-row), 8192 elems (16KB) per tile,
// contiguous. Element (r,c) at r*64 + XOR-swizzled column (by r&7) so MFMA
// fragment ds_read_b128 are bank-conflict-free. DMA copies tiles verbatim.
// ---------------------------------------------------------------------------
__device__ __forceinline__ int tp_off(int r, int c) {
  return r * 64 + ((((c >> 3) ^ (r & 7)) << 3) | (c & 7));
}
__device__ __forceinline__ size_t tp_idx(int row, int col, int KT) {
  return ((size_t)((row >> 7) * KT + (col >> 6)) << 13) + tp_off(row & 127, col & 63);
}

// Async global->LDS DMA, 16B/lane; LDS dest is wave-uniform base + lane*16.
__device__ __forceinline__ void gl_lds16(const ushort* g, ushort* l) {
  __builtin_amdgcn_global_load_lds(
      (const __attribute__((address_space(1))) void*)g,
      (__attribute__((address_space(3))) void*)l, 16, 0, 0);
}

// ---------------------------------------------------------------------------
// TP MFMA K-loop: nkt tiles of K=64. Each wave DMA-stages a contiguous 4KB
// quarter of each 16KB tile. 4 waves: 64x64 C-quadrants via 16x16x32 MFMA.
// ---------------------------------------------------------------------------
template<bool DUAL>
__device__ __forceinline__ void mfma_tp(
    const ushort* __restrict__ aT, const ushort* __restrict__ b1T,
    const ushort* __restrict__ b3T, int nkt,
    ushort* As, ushort* Bs1, ushort* Bs3,
    f4_t acc1[4][4], f4_t acc3[4][4], int tid)
{
  const int lane = tid & 63, w = tid >> 6;
  const int wm = w & 1, wn = w >> 1;
  const int quad = lane >> 4, lr = lane & 15;
  const int soff = w << 11;          // wave's 2048-elem quarter
  const int l8 = lane * 8;

  for (int kt = 0; kt < nkt; kt++) {
    const size_t tb = (size_t)kt << 13;
    const ushort* ga = aT + tb + soff + l8;
    const ushort* gb = b1T + tb + soff + l8;
    #pragma unroll
    for (int d = 0; d < 4; d++) {
      gl_lds16(ga + (d << 9), As  + soff + (d << 9));
      gl_lds16(gb + (d << 9), Bs1 + soff + (d << 9));
    }
    if (DUAL) {
      const ushort* gc = b3T + tb + soff + l8;
      #pragma unroll
      for (int d = 0; d < 4; d++)
        gl_lds16(gc + (d << 9), Bs3 + soff + (d << 9));
    }
    __syncthreads();
    #pragma unroll
    for (int half = 0; half < 2; half++) {
      const int ch = (half << 2) + quad;   // k-chunk index 0..7
      bf8_t af[4];
      #pragma unroll
      for (int mi = 0; mi < 4; mi++) {
        const int r = wm * 64 + mi * 16 + lr;
        af[mi] = *(const bf8_t*)&As[r * 64 + ((ch ^ (r & 7)) << 3)];
      }
      #pragma unroll
      for (int ni = 0; ni < 4; ni++) {
        const int n = wn * 64 + ni * 16 + lr;
        bf8_t b1 = *(const bf8_t*)&Bs1[n * 64 + ((ch ^ (n & 7)) << 3)];
        #pragma unroll
        for (int mi = 0; mi < 4; mi++)
          acc1[mi][ni] = __builtin_amdgcn_mfma_f32_16x16x32_bf16(af[mi], b1, acc1[mi][ni], 0, 0, 0);
        if (DUAL) {
          bf8_t b3 = *(const bf8_t*)&Bs3[n * 64 + ((ch ^ (n & 7)) << 3)];
          #pragma unroll
          for (int mi = 0; mi < 4; mi++)
            acc3[mi][ni] = __builtin_amdgcn_mfma_f32_16x16x32_bf16(af[mi], b3, acc3[mi][ni], 0, 0, 0);
        }
      }
    }
    __syncthreads();
  }
}

// ---------------------------------------------------------------------------
// Cast emb+x to bf16: flat [row][k] copies (for the gather) + TP emb
// ---------------------------------------------------------------------------
__global__ void cast_ax(const float* __restrict__ e_, const float* __restrict__ x_,
                        ushort* __restrict__ embf, ushort* __restrict__ xf,
                        ushort* __restrict__ etp)
{
  const int NC = (T_TOK * DIM) / 8;
  const int stride = gridDim.x * blockDim.x;
  for (int c = blockIdx.x * blockDim.x + threadIdx.x; c < 2 * NC; c += stride) {
    const bool isE = c < NC;
    const int g = (isE ? c : c - NC) << 3;
    const float* src = isE ? e_ : x_;
    const float4 v0 = *(const float4*)(src + g);
    const float4 v1 = *(const float4*)(src + g + 4);
    ushort t[8];
    t[0] = f2b(v0.x); t[1] = f2b(v0.y); t[2] = f2b(v0.z); t[3] = f2b(v0.w);
    t[4] = f2b(v1.x); t[5] = f2b(v1.y); t[6] = f2b(v1.z); t[7] = f2b(v1.w);
    ushort* flat = isE ? embf : xf;
    *(uint4*)(flat + g) = *(uint4*)t;
    if (isE) {
      const int row = g >> 10, col = g & 1023;
      *(uint4*)&etp[tp_idx(row, col, 16)] = *(uint4*)t;
    }
  }
}

// ---------------------------------------------------------------------------
// Transpose + cast + TP-pack: src fp32 [z][R][C] -> logical [z][C][R] TP.
// Generic (used for sW1/sW2).
// ---------------------------------------------------------------------------
__device__ __forceinline__ void tr_body(const float* __restrict__ src,
                                        ushort* __restrict__ dst,
                                        int R, int C, int zz, int bx, int by, int tid)
{
  __shared__ float t[64 * 65];
  const size_t mb = (size_t)zz * R * C;
  const int r0 = by * 64, c0 = bx * 64;
  {
    const int row = tid >> 4;
    const int c4  = (tid & 15) * 4;
    #pragma unroll
    for (int p = 0; p < 4; p++) {
      const int r = p * 16 + row;
      const float4 v = *(const float4*)(src + mb + (size_t)(r0 + r) * C + c0 + c4);
      t[r * 65 + c4 + 0] = v.x; t[r * 65 + c4 + 1] = v.y;
      t[r * 65 + c4 + 2] = v.z; t[r * 65 + c4 + 3] = v.w;
    }
  }
  __syncthreads();
  {
    const int KT = R >> 6;
    const int oc  = tid >> 2;
    const int seg = (tid & 3) * 16;
    const int n = c0 + oc;
    ushort tmp[16];
    #pragma unroll
    for (int i = 0; i < 16; i++) tmp[i] = f2b(t[(seg + i) * 65 + oc]);
    *(uint4*)&dst[mb + tp_idx(n, r0 + seg, KT)]     = *(uint4*)&tmp[0];
    *(uint4*)&dst[mb + tp_idx(n, r0 + seg + 8, KT)] = *(uint4*)&tmp[8];
  }
}

__global__ void transpose_cast_tp(const float* __restrict__ src, ushort* __restrict__ dst,
                                  int R, int C)
{
  tr_body(src, dst, R, C, blockIdx.z, blockIdx.x, blockIdx.y, threadIdx.x);
}

// Merged W1/W3/W2 transpose: z in [0,48), all slices are 1024x1024.
__global__ void transpose_w123(const float* __restrict__ W1, const float* __restrict__ W3,
                               const float* __restrict__ W2,
                               ushort* __restrict__ w1tp, ushort* __restrict__ w3tp,
                               ushort* __restrict__ w2tp)
{
  const int z = blockIdx.z;
  const float* src = (z < 16) ? W1 : (z < 32) ? W3 : W2;
  ushort* dst = (z < 16) ? w1tp : (z < 32) ? w3tp : w2tp;
  tr_body(src, dst, 1024, 1024, z & 15, blockIdx.x, blockIdx.y, threadIdx.x);
}

// ---------------------------------------------------------------------------
// Gate: fp32 softmax(emb @ gate_w^T), top-2, per-expert compact lists.
// Dot product fully unrolled as 16 independent float4 loads per lane.
// ---------------------------------------------------------------------------
__global__ void gate_topk(const float* __restrict__ emb, const float* __restrict__ gw,
                          int* __restrict__ cnt, int* __restrict__ list, float* __restrict__ wl)
{
  __shared__ float se[DIM];
  __shared__ float sc[NEXP];
  const int tok = blockIdx.x;
  const int t = threadIdx.x;
  ((float4*)se)[t] = ((const float4*)(emb + (size_t)tok * DIM))[t];
  __syncthreads();
  const int e = t >> 4, l = t & 15;
  const float* g = gw + e * DIM + l * 4;
  const float* s = se + l * 4;
  float p = 0.f;
  #pragma unroll
  for (int j = 0; j < 16; j++) {          // 16 independent 16B loads in flight
    const float4 gv = *(const float4*)(g + j * 64);
    const float4 sv = *(const float4*)(s + j * 64);
    p += gv.x * sv.x + gv.y * sv.y + gv.z * sv.z + gv.w * sv.w;
  }
  p += __shfl_xor(p, 1); p += __shfl_xor(p, 2);
  p += __shfl_xor(p, 4); p += __shfl_xor(p, 8);
  if (l == 0) sc[e] = p;
  __syncthreads();
  if (t == 0) {
    float m = sc[0];
    #pragma unroll
    for (int j = 1; j < NEXP; j++) m = fmaxf(m, sc[j]);
    float pr[NEXP]; float sum = 0.f;
    #pragma unroll
    for (int j = 0; j < NEXP; j++) { pr[j] = __expf(sc[j] - m); sum += pr[j]; }
    const float inv = 1.0f / sum;
    int i0 = 0; float b0 = pr[0];
    #pragma unroll
    for (int j = 1; j < NEXP; j++) if (pr[j] > b0) { b0 = pr[j]; i0 = j; }
    int i1 = -1; float b1 = -1.f;
    #pragma unroll
    for (int j = 0; j < NEXP; j++) if (j != i0 && pr[j] > b1) { b1 = pr[j]; i1 = j; }
    const int p0 = atomicAdd(&cnt[i0], 1);
    list[i0 * T_TOK + p0] = tok; wl[i0 * T_TOK + p0] = b0 * inv;
    const int p1 = atomicAdd(&cnt[i1], 1);
    list[i1 * T_TOK + p1] = tok; wl[i1 * T_TOK + p1] = b1 * inv;
  }
}

// offp[e] = 128-aligned prefix sum; offp[17] = #m-tiles; tbl[2*mt] = {e, row0}
__global__ void scan_offs(const int* __restrict__ cnt, int* __restrict__ offp,
                          int* __restrict__ tbl)
{
  if (blockIdx.x == 0 && threadIdx.x == 0) {
    int a = 0, nm = 0;
    for (int e = 0; e < NEXP; e++) {
      offp[e] = a;
      const int c = (cnt[e] + 127) & ~127;
      for (int r = 0; r < c; r += 128) { tbl[2 * nm] = e; tbl[2 * nm + 1] = a + r; nm++; }
      a += c;
    }
    offp[NEXP] = a;
    offp[NEXP + 1] = nm;
  }
}

// ---------------------------------------------------------------------------
// Gather routed A rows into TP compact form (pad slots -> zeros). One block
// per real m-tile (table-driven).
// ---------------------------------------------------------------------------
__global__ void gather_a(const ushort* __restrict__ embf, const ushort* __restrict__ xf,
                         const int* __restrict__ cnt, const int* __restrict__ offp,
                         const int* __restrict__ tbl, const int* __restrict__ list,
                         ushort* __restrict__ ag)
{
  const int mt = blockIdx.x;
  if (mt >= offp[NEXP + 1]) return;
  const int e = tbl[2 * mt], row0 = tbl[2 * mt + 1];
  const int ce = cnt[e];
  const int s0 = row0 - offp[e];
  const ushort* src = (e < NIN) ? xf : embf;
  const int tid = threadIdx.x;
  for (int rep = 0; rep < 64; rep++) {
    const int lin = rep * 256 + tid;
    const int r = lin >> 7, c8 = (lin & 127) << 3;
    const int s = s0 + r;
    uint4 v = make_uint4(0u, 0u, 0u, 0u);
    if (s < ce) {
      const int tok = list[e * T_TOK + s];
      v = *(const uint4*)&src[(size_t)tok * DIM + c8];
    }
    *(uint4*)&ag[tp_idx(row0 + r, c8, 16)] = v;
  }
}

// ---------------------------------------------------------------------------
// Stage 1, flat grid: b < 512 -> shared front (hs TP); else routed SwiGLU
// front (h TP), table-driven m-tiles (tiny early-exit tail at the very end).
// ---------------------------------------------------------------------------
__launch_bounds__(256, 2)
__global__ void stage1(const ushort* __restrict__ ag, const ushort* __restrict__ etp,
                       const ushort* __restrict__ w1tp, const ushort* __restrict__ w3tp,
                       const ushort* __restrict__ sw1tp,
                       const float* __restrict__ B1, const float* __restrict__ B3,
                       const float* __restrict__ sB1,
                       const int* __restrict__ offp, const int* __restrict__ tbl,
                       ushort* __restrict__ h_tp, ushort* __restrict__ hs_tp)
{
  __shared__ ushort As[8192], Bs1[8192], Bs3[8192];
  const int tid = threadIdx.x;
  const int lane = tid & 63, w = tid >> 6;
  const int wm = w & 1, wn = w >> 1;
  const int quad = lane >> 4, lr = lane & 15;
  const int b = blockIdx.x;

  f4_t acc1[4][4], acc3[4][4];
  const f4_t fz = {0.f, 0.f, 0.f, 0.f};
  #pragma unroll
  for (int i = 0; i < 4; i++)
    #pragma unroll
    for (int j = 0; j < 4; j++) { acc1[i][j] = fz; acc3[i][j] = fz; }

  if (b < 512) {                       // ---- shared expert front: all real
    const int m0 = (b >> 4) << 7;
    const int n0 = (b & 15) << 7;
    const ushort* aT = etp + ((size_t)((m0 >> 7) * 16) << 13);
    const ushort* bT = sw1tp + ((size_t)((n0 >> 7) * 16) << 13);
    mfma_tp<false>(aT, bT, nullptr, 16, As, Bs1, Bs3, acc1, acc3, tid);
    #pragma unroll
    for (int mi = 0; mi < 4; mi++) {
      #pragma unroll
      for (int r = 0; r < 4; r++) {
        const int row = m0 + wm * 64 + mi * 16 + quad * 4 + r;
        #pragma unroll
        for (int ni = 0; ni < 4; ni++) {
          const int col = n0 + wn * 64 + ni * 16 + lr;
          const float v = acc1[mi][ni][r] + sB1[col];
          const float sg = 1.0f / (1.0f + __expf(-v));
          hs_tp[tp_idx(row, col, 32)] = f2b(v * sg);
        }
      }
    }
  } else {                             // ---- routed SwiGLU front
    const int t = b - 512;
    const int mt = t >> 3;
    if (mt >= offp[NEXP + 1]) return;
    const int n0 = (t & 7) << 7;
    const int e = tbl[2 * mt], row0 = tbl[2 * mt + 1];
    const ushort* aT  = ag + ((size_t)((row0 >> 7) * 16) << 13);
    const ushort* b1T = w1tp + ((size_t)e << 20) + ((size_t)((n0 >> 7) * 16) << 13);
    const ushort* b3T = w3tp + ((size_t)e << 20) + ((size_t)((n0 >> 7) * 16) << 13);
    mfma_tp<true>(aT, b1T, b3T, 16, As, Bs1, Bs3, acc1, acc3, tid);
    #pragma unroll
    for (int mi = 0; mi < 4; mi++) {
      #pragma unroll
      for (int r = 0; r < 4; r++) {
        const int grow = row0 + wm * 64 + mi * 16 + quad * 4 + r;
        #pragma unroll
        for (int ni = 0; ni < 4; ni++) {
          const int col = n0 + wn * 64 + ni * 16 + lr;
          const float v1 = acc1[mi][ni][r] + B1[e * HID + col];
          const float v3 = acc3[mi][ni][r] + B3[e * HID + col];
          const float sg = 1.0f / (1.0f + __expf(-v1));
          h_tp[tp_idx(grow, col, 16)] = f2b(v1 * sg * v3);
        }
      }
    }
  }
}

// ---------------------------------------------------------------------------
// Stage 2, flat grid: b < 256 -> shared back; else routed back (table-driven).
// Both atomicAdd into zero-inited y.
// ---------------------------------------------------------------------------
__launch_bounds__(256, 3)
__global__ void stage2(const ushort* __restrict__ h_tp, const ushort* __restrict__ hs_tp,
                       const ushort* __restrict__ w2tp, const ushort* __restrict__ sw2tp,
                       const float* __restrict__ B2, const float* __restrict__ sB2,
                       const int* __restrict__ cnt, const int* __restrict__ offp,
                       const int* __restrict__ tbl, const int* __restrict__ list,
                       const float* __restrict__ wl, float* __restrict__ y)
{
  __shared__ ushort As[8192], Bs[8192];
  const int tid = threadIdx.x;
  const int lane = tid & 63, w = tid >> 6;
  const int wm = w & 1, wn = w >> 1;
  const int quad = lane >> 4, lr = lane & 15;
  const int b = blockIdx.x;

  f4_t acc[4][4];
  const f4_t fz = {0.f, 0.f, 0.f, 0.f};
  #pragma unroll
  for (int i = 0; i < 4; i++)
    #pragma unroll
    for (int j = 0; j < 4; j++) acc[i][j] = fz;

  if (b < 256) {                       // ---- shared expert back (K=2048)
    const int m0 = (b >> 3) << 7;
    const int n0 = (b & 7) << 7;
    const ushort* aT = hs_tp + ((size_t)((m0 >> 7) * 32) << 13);
    const ushort* bT = sw2tp + ((size_t)((n0 >> 7) * 32) << 13);
    mfma_tp<false>(aT, bT, nullptr, 32, As, Bs, Bs, acc, acc, tid);
    #pragma unroll
    for (int mi = 0; mi < 4; mi++) {
      #pragma unroll
      for (int r = 0; r < 4; r++) {
        const int row = m0 + wm * 64 + mi * 16 + quad * 4 + r;
        float* yr = y + (size_t)row * DIM;
        #pragma unroll
        for (int ni = 0; ni < 4; ni++) {
          const int col = n0 + wn * 64 + ni * 16 + lr;
          atomicAdd(&yr[col], acc[mi][ni][r] + sB2[col]);
        }
      }
    }
  } else {                             // ---- routed back (K=1024)
    const int t = b - 256;
    const int mt = t >> 3;
    if (mt >= offp[NEXP + 1]) return;
    const int n0 = (t & 7) << 7;
    const int e = tbl[2 * mt], row0 = tbl[2 * mt + 1];
    const int ce = cnt[e];
    const int s0 = row0 - offp[e];
    const ushort* aT = h_tp + ((size_t)((row0 >> 7) * 16) << 13);
    const ushort* bT = w2tp + ((size_t)e << 20) + ((size_t)((n0 >> 7) * 16) << 13);
    mfma_tp<false>(aT, bT, nullptr, 16, As, Bs, Bs, acc, acc, tid);
    #pragma unroll
    for (int mi = 0; mi < 4; mi++) {
      #pragma unroll
      for (int r = 0; r < 4; r++) {
        const int rowl = s0 + wm * 64 + mi * 16 + quad * 4 + r;
        if (rowl < ce) {
          const int tok = list[e * T_TOK + rowl];
          const float wgt = wl[e * T_TOK + rowl];
          float* yr = y + (size_t)tok * DIM;
          #pragma unroll
          for (int ni = 0; ni < 4; ni++) {
            const int col = n0 + wn * 64 + ni * 16 + lr;
            atomicAdd(&yr[col], wgt * (acc[mi][ni][r] + B2[e * DIM + col]));
          }
        }
      }
    }
  }
}

// ---------------------------------------------------------------------------
// Launch
// ---------------------------------------------------------------------------
extern "C" void kernel_launch(void* const* d_in, const int* in_sizes, int n_in,
                              void* d_out, int out_size, void* d_ws, size_t ws_size,
                              hipStream_t stream)
{
  const float* emb = (const float*)d_in[0];
  const float* x   = (const float*)d_in[1];
  const float* gw  = (const float*)d_in[2];
  const float* W1  = (const float*)d_in[3];
  const float* B1  = (const float*)d_in[4];
  const float* W2  = (const float*)d_in[5];
  const float* B2  = (const float*)d_in[6];
  const float* W3  = (const float*)d_in[7];
  const float* B3  = (const float*)d_in[8];
  const float* sW1 = (const float*)d_in[9];
  const float* sB1 = (const float*)d_in[10];
  const float* sW2 = (const float*)d_in[11];
  const float* sB2 = (const float*)d_in[12];
  float* y = (float*)d_out;

  char* ws = (char*)d_ws;
  const size_t MB = 1024ULL * 1024ULL;
  ushort* embf  = (ushort*)(ws + 0);        // [4096][1024] flat
  ushort* xf    = (ushort*)(ws + 8 * MB);   // [4096][1024] flat
  ushort* etp   = (ushort*)(ws + 16 * MB);  // emb TP (KT=16)
  ushort* w1tp  = (ushort*)(ws + 24 * MB);  // [16] x TP [1024n][1024k]
  ushort* w3tp  = (ushort*)(ws + 56 * MB);
  ushort* w2tp  = (ushort*)(ws + 88 * MB);  // [16] x TP [1024n][1024k]
  ushort* sw1tp = (ushort*)(ws + 120 * MB); // TP [2048n][1024k]
  ushort* sw2tp = (ushort*)(ws + 124 * MB); // TP [1024n][2048k]
  ushort* ag    = (ushort*)(ws + 128 * MB); // gathered A, TP, <=10240 rows
  ushort* h_tp  = (ushort*)(ws + 148 * MB); // routed hidden, TP, <=10240 rows
  ushort* hs_tp = (ushort*)(ws + 168 * MB); // shared hidden, TP [4096][2048]
  int*   cnt    = (int*)(ws + 184 * MB);    // [16]
  int*   offp   = cnt + 16;                 // [18]  (offp[17] = #m-tiles)
  int*   tbl    = offp + 18;                // [2*MT_MAX]
  int*   list   = (int*)(ws + 184 * MB + 1024);
  float* wl     = (float*)(ws + 184 * MB + 1024 + 262144);

  hipMemsetAsync(cnt, 0, 64, stream);
  hipMemsetAsync(y, 0, (size_t)T_TOK * DIM * sizeof(float), stream);
  cast_ax<<<1024, 256, 0, stream>>>(emb, x, embf, xf, etp);
  transpose_w123<<<dim3(16, 16, 48), 256, 0, stream>>>(W1, W3, W2, w1tp, w3tp, w2tp);
  transpose_cast_tp<<<dim3(32, 16, 1), 256, 0, stream>>>(sW1, sw1tp, DIM, HSH);
  transpose_cast_tp<<<dim3(16, 32, 1), 256, 0, stream>>>(sW2, sw2tp, HSH, DIM);
  gate_topk<<<T_TOK, 256, 0, stream>>>(emb, gw, cnt, list, wl);
  scan_offs<<<1, 64, 0, stream>>>(cnt, offp, tbl);
  gather_a<<<MT_MAX, 256, 0, stream>>>(embf, xf, cnt, offp, tbl, list, ag);
  stage1<<<512 + MT_MAX * 8, 256, 0, stream>>>(ag, etp, w1tp, w3tp, sw1tp,
                                               B1, B3, sB1, offp, tbl, h_tp, hs_tp);
  stage2<<<256 + MT_MAX * 8, 256, 0, stream>>>(h_tp, hs_tp, w2tp, sw2tp, B2, sB2,
                                               cnt, offp, tbl, list, wl, y);
}

// Round 6
// 595.720 us; speedup vs baseline: 1.8932x; 1.0681x over previous
//
#include <hip/hip_runtime.h>

// Problem constants (fixed by the reference)
#define T_TOK 4096   // B*S tokens
#define DIM   1024   // model dim D
#define HID   1024   // expert hidden H
#define NEXP  16     // routed experts
#define HSH   2048   // shared hidden = NSH*H
#define NIN   2      // experts that consume x instead of emb
#define MT_MAX 80    // max routed m-tiles: (8192 + 16*127)/128 rounded up

typedef __attribute__((ext_vector_type(8))) short bf8_t;  // 8 x bf16 (MFMA A/B frag)
typedef __attribute__((ext_vector_type(4))) float f4_t;   // 4 x f32  (MFMA C/D frag)

__device__ __forceinline__ ushort f2b(float f) {  // f32 -> bf16 RNE
  unsigned u = __float_as_uint(f);
  u = (u + 0x7FFFu + ((u >> 16) & 1u)) >> 16;
  return (ushort)u;
}

// ---------------------------------------------------------------------------
// Tile-packed (TP) layout: matrix [NR][NK] stored as 128x64 tiles, row-major
// tile grid (KT = NK/64 tiles per tile-row), 8192 elems (16KB) per tile,
// contiguous. Element (r,c) at r*64 + XOR-swizzled column (by r&7) so MFMA
// fragment ds_read_b128 are bank-conflict-free. DMA copies tiles verbatim.
// ---------------------------------------------------------------------------
__device__ __forceinline__ int tp_off(int r, int c) {
  return r * 64 + ((((c >> 3) ^ (r & 7)) << 3) | (c & 7));
}
__device__ __forceinline__ size_t tp_idx(int row, int col, int KT) {
  return ((size_t)((row >> 7) * KT + (col >> 6)) << 13) + tp_off(row & 127, col & 63);
}

// Async global->LDS DMA, 16B/lane; LDS dest is wave-uniform base + lane*16.
__device__ __forceinline__ void gl_lds16(const ushort* g, ushort* l) {
  __builtin_amdgcn_global_load_lds(
      (const __attribute__((address_space(1))) void*)g,
      (__attribute__((address_space(3))) void*)l, 16, 0, 0);
}

// ---------------------------------------------------------------------------
// TP MFMA K-loop: nkt tiles of K=64. Each wave DMA-stages a contiguous 4KB
// quarter of each 16KB tile. 4 waves: 64x64 C-quadrants via 16x16x32 MFMA.
// ---------------------------------------------------------------------------
template<bool DUAL>
__device__ __forceinline__ void mfma_tp(
    const ushort* __restrict__ aT, const ushort* __restrict__ b1T,
    const ushort* __restrict__ b3T, int nkt,
    ushort* As, ushort* Bs1, ushort* Bs3,
    f4_t acc1[4][4], f4_t acc3[4][4], int tid)
{
  const int lane = tid & 63, w = tid >> 6;
  const int wm = w & 1, wn = w >> 1;
  const int quad = lane >> 4, lr = lane & 15;
  const int soff = w << 11;          // wave's 2048-elem quarter
  const int l8 = lane * 8;

  for (int kt = 0; kt < nkt; kt++) {
    const size_t tb = (size_t)kt << 13;
    const ushort* ga = aT + tb + soff + l8;
    const ushort* gb = b1T + tb + soff + l8;
    #pragma unroll
    for (int d = 0; d < 4; d++) {
      gl_lds16(ga + (d << 9), As  + soff + (d << 9));
      gl_lds16(gb + (d << 9), Bs1 + soff + (d << 9));
    }
    if (DUAL) {
      const ushort* gc = b3T + tb + soff + l8;
      #pragma unroll
      for (int d = 0; d < 4; d++)
        gl_lds16(gc + (d << 9), Bs3 + soff + (d << 9));
    }
    __syncthreads();
    #pragma unroll
    for (int half = 0; half < 2; half++) {
      const int ch = (half << 2) + quad;   // k-chunk index 0..7
      bf8_t af[4];
      #pragma unroll
      for (int mi = 0; mi < 4; mi++) {
        const int r = wm * 64 + mi * 16 + lr;
        af[mi] = *(const bf8_t*)&As[r * 64 + ((ch ^ (r & 7)) << 3)];
      }
      #pragma unroll
      for (int ni = 0; ni < 4; ni++) {
        const int n = wn * 64 + ni * 16 + lr;
        bf8_t b1 = *(const bf8_t*)&Bs1[n * 64 + ((ch ^ (n & 7)) << 3)];
        #pragma unroll
        for (int mi = 0; mi < 4; mi++)
          acc1[mi][ni] = __builtin_amdgcn_mfma_f32_16x16x32_bf16(af[mi], b1, acc1[mi][ni], 0, 0, 0);
        if (DUAL) {
          bf8_t b3 = *(const bf8_t*)&Bs3[n * 64 + ((ch ^ (n & 7)) << 3)];
          #pragma unroll
          for (int mi = 0; mi < 4; mi++)
            acc3[mi][ni] = __builtin_amdgcn_mfma_f32_16x16x32_bf16(af[mi], b3, acc3[mi][ni], 0, 0, 0);
        }
      }
    }
    __syncthreads();
  }
}

// ---------------------------------------------------------------------------
// Transpose+cast+TP-pack body (shared buffer passed in): fp32 [R][C] slice zz
// -> logical [C][R] TP.
// ---------------------------------------------------------------------------
__device__ __forceinline__ void tr_body(const float* __restrict__ src,
                                        ushort* __restrict__ dst,
                                        int R, int C, int zz, int bx, int by, int tid,
                                        float* t)
{
  const size_t mb = (size_t)zz * R * C;
  const int r0 = by * 64, c0 = bx * 64;
  {
    const int row = tid >> 4;
    const int c4  = (tid & 15) * 4;
    #pragma unroll
    for (int p = 0; p < 4; p++) {
      const int r = p * 16 + row;
      const float4 v = *(const float4*)(src + mb + (size_t)(r0 + r) * C + c0 + c4);
      t[r * 65 + c4 + 0] = v.x; t[r * 65 + c4 + 1] = v.y;
      t[r * 65 + c4 + 2] = v.z; t[r * 65 + c4 + 3] = v.w;
    }
  }
  __syncthreads();
  {
    const int KT = R >> 6;
    const int oc  = tid >> 2;
    const int seg = (tid & 3) * 16;
    const int n = c0 + oc;
    ushort tmp[16];
    #pragma unroll
    for (int i = 0; i < 16; i++) tmp[i] = f2b(t[(seg + i) * 65 + oc]);
    *(uint4*)&dst[mb + tp_idx(n, r0 + seg, KT)]     = *(uint4*)&tmp[0];
    *(uint4*)&dst[mb + tp_idx(n, r0 + seg + 8, KT)] = *(uint4*)&tmp[8];
  }
}

// ---------------------------------------------------------------------------
// MEGA-PREP: one flat dispatch covering gate + casts + all weight transposes.
//   [0,4096)        gate_topk (fp32 softmax + top-2 + compact lists)
//   [4096,5120)     cast emb+x -> bf16 flat (+ TP emb)
//   [5120,17408)    W1/W3/W2 transpose->TP (48 slices x 256 tiles)
//   [17408,17920)   sW1 transpose->TP
//   [17920,18432)   sW2 transpose->TP
// ---------------------------------------------------------------------------
#define PREP_BLOCKS 18432
__global__ void prep(const float* __restrict__ emb, const float* __restrict__ x_,
                     const float* __restrict__ gw,
                     const float* __restrict__ W1, const float* __restrict__ W3,
                     const float* __restrict__ W2,
                     const float* __restrict__ sW1, const float* __restrict__ sW2,
                     ushort* __restrict__ embf, ushort* __restrict__ xf,
                     ushort* __restrict__ etp,
                     ushort* __restrict__ w1tp, ushort* __restrict__ w3tp,
                     ushort* __restrict__ w2tp,
                     ushort* __restrict__ sw1tp, ushort* __restrict__ sw2tp,
                     int* __restrict__ cnt, int* __restrict__ list,
                     float* __restrict__ wl)
{
  __shared__ float smem[64 * 65 + 16];
  const int b = blockIdx.x;
  const int t = threadIdx.x;

  if (b < 4096) {
    // ---------------- gate ----------------
    float* se = smem;                 // [1024]
    float* sc = smem + 64 * 65;       // [16]
    const int tok = b;
    ((float4*)se)[t] = ((const float4*)(emb + (size_t)tok * DIM))[t];
    __syncthreads();
    const int e = t >> 4, l = t & 15;
    const float* g = gw + e * DIM + l * 4;
    const float* s = se + l * 4;
    float p = 0.f;
    #pragma unroll
    for (int j = 0; j < 16; j++) {
      const float4 gv = *(const float4*)(g + j * 64);
      const float4 sv = *(const float4*)(s + j * 64);
      p += gv.x * sv.x + gv.y * sv.y + gv.z * sv.z + gv.w * sv.w;
    }
    p += __shfl_xor(p, 1); p += __shfl_xor(p, 2);
    p += __shfl_xor(p, 4); p += __shfl_xor(p, 8);
    if (l == 0) sc[e] = p;
    __syncthreads();
    if (t == 0) {
      float m = sc[0];
      #pragma unroll
      for (int j = 1; j < NEXP; j++) m = fmaxf(m, sc[j]);
      float pr[NEXP]; float sum = 0.f;
      #pragma unroll
      for (int j = 0; j < NEXP; j++) { pr[j] = __expf(sc[j] - m); sum += pr[j]; }
      const float inv = 1.0f / sum;
      int i0 = 0; float b0 = pr[0];
      #pragma unroll
      for (int j = 1; j < NEXP; j++) if (pr[j] > b0) { b0 = pr[j]; i0 = j; }
      int i1 = -1; float b1 = -1.f;
      #pragma unroll
      for (int j = 0; j < NEXP; j++) if (j != i0 && pr[j] > b1) { b1 = pr[j]; i1 = j; }
      const int p0 = atomicAdd(&cnt[i0], 1);
      list[i0 * T_TOK + p0] = tok; wl[i0 * T_TOK + p0] = b0 * inv;
      const int p1 = atomicAdd(&cnt[i1], 1);
      list[i1 * T_TOK + p1] = tok; wl[i1 * T_TOK + p1] = b1 * inv;
    }
  } else if (b < 5120) {
    // ---------------- cast emb + x ----------------
    const int NC = (T_TOK * DIM) / 8;  // 8-elem chunks per matrix
    const int c0 = (b - 4096) * 256 + t;
    for (int c = c0; c < 2 * NC; c += 1024 * 256) {
      const bool isE = c < NC;
      const int g = (isE ? c : c - NC) << 3;
      const float* src = isE ? emb : x_;
      const float4 v0 = *(const float4*)(src + g);
      const float4 v1 = *(const float4*)(src + g + 4);
      ushort tt[8];
      tt[0] = f2b(v0.x); tt[1] = f2b(v0.y); tt[2] = f2b(v0.z); tt[3] = f2b(v0.w);
      tt[4] = f2b(v1.x); tt[5] = f2b(v1.y); tt[6] = f2b(v1.z); tt[7] = f2b(v1.w);
      ushort* flat = isE ? embf : xf;
      *(uint4*)(flat + g) = *(uint4*)tt;
      if (isE) {
        const int row = g >> 10, col = g & 1023;
        *(uint4*)&etp[tp_idx(row, col, 16)] = *(uint4*)tt;
      }
    }
  } else if (b < 17408) {
    // ---------------- W1/W3/W2 transpose ----------------
    const int r = b - 5120;
    const int z = r >> 8, rem = r & 255;
    const float* src = (z < 16) ? W1 : (z < 32) ? W3 : W2;
    ushort* dst = (z < 16) ? w1tp : (z < 32) ? w3tp : w2tp;
    tr_body(src, dst, 1024, 1024, z & 15, rem & 15, rem >> 4, t, smem);
  } else if (b < 17920) {
    // ---------------- sW1 transpose (R=1024, C=2048) ----------------
    const int r = b - 17408;
    tr_body(sW1, sw1tp, DIM, HSH, 0, r & 31, r >> 5, t, smem);
  } else {
    // ---------------- sW2 transpose (R=2048, C=1024) ----------------
    const int r = b - 17920;
    tr_body(sW2, sw2tp, HSH, DIM, 0, r & 15, r >> 4, t, smem);
  }
}

// offp[e] = 128-aligned prefix sum; offp[17] = #m-tiles; tbl[2*mt] = {e, row0}
__global__ void scan_offs(const int* __restrict__ cnt, int* __restrict__ offp,
                          int* __restrict__ tbl)
{
  if (blockIdx.x == 0 && threadIdx.x == 0) {
    int a = 0, nm = 0;
    for (int e = 0; e < NEXP; e++) {
      offp[e] = a;
      const int c = (cnt[e] + 127) & ~127;
      for (int r = 0; r < c; r += 128) { tbl[2 * nm] = e; tbl[2 * nm + 1] = a + r; nm++; }
      a += c;
    }
    offp[NEXP] = a;
    offp[NEXP + 1] = nm;
  }
}

// ---------------------------------------------------------------------------
// Gather routed A rows into TP compact form (pad slots -> zeros). One block
// per real m-tile (table-driven).
// ---------------------------------------------------------------------------
__global__ void gather_a(const ushort* __restrict__ embf, const ushort* __restrict__ xf,
                         const int* __restrict__ cnt, const int* __restrict__ offp,
                         const int* __restrict__ tbl, const int* __restrict__ list,
                         ushort* __restrict__ ag)
{
  const int mt = blockIdx.x;
  if (mt >= offp[NEXP + 1]) return;
  const int e = tbl[2 * mt], row0 = tbl[2 * mt + 1];
  const int ce = cnt[e];
  const int s0 = row0 - offp[e];
  const ushort* src = (e < NIN) ? xf : embf;
  const int tid = threadIdx.x;
  for (int rep = 0; rep < 64; rep++) {
    const int lin = rep * 256 + tid;
    const int r = lin >> 7, c8 = (lin & 127) << 3;
    const int s = s0 + r;
    uint4 v = make_uint4(0u, 0u, 0u, 0u);
    if (s < ce) {
      const int tok = list[e * T_TOK + s];
      v = *(const uint4*)&src[(size_t)tok * DIM + c8];
    }
    *(uint4*)&ag[tp_idx(row0 + r, c8, 16)] = v;
  }
}

// ---------------------------------------------------------------------------
// Stage 1, flat grid: b < 512 -> shared front (hs TP); else routed SwiGLU
// front (h TP), table-driven m-tiles (tiny early-exit tail at the very end).
// 48KB LDS x 3 blocks/CU = 144KB.
// ---------------------------------------------------------------------------
__launch_bounds__(256, 3)
__global__ void stage1(const ushort* __restrict__ ag, const ushort* __restrict__ etp,
                       const ushort* __restrict__ w1tp, const ushort* __restrict__ w3tp,
                       const ushort* __restrict__ sw1tp,
                       const float* __restrict__ B1, const float* __restrict__ B3,
                       const float* __restrict__ sB1,
                       const int* __restrict__ offp, const int* __restrict__ tbl,
                       ushort* __restrict__ h_tp, ushort* __restrict__ hs_tp)
{
  __shared__ ushort As[8192], Bs1[8192], Bs3[8192];
  const int tid = threadIdx.x;
  const int lane = tid & 63, w = tid >> 6;
  const int wm = w & 1, wn = w >> 1;
  const int quad = lane >> 4, lr = lane & 15;
  const int b = blockIdx.x;

  f4_t acc1[4][4], acc3[4][4];
  const f4_t fz = {0.f, 0.f, 0.f, 0.f};
  #pragma unroll
  for (int i = 0; i < 4; i++)
    #pragma unroll
    for (int j = 0; j < 4; j++) { acc1[i][j] = fz; acc3[i][j] = fz; }

  if (b < 512) {                       // ---- shared expert front: all real
    const int m0 = (b >> 4) << 7;
    const int n0 = (b & 15) << 7;
    const ushort* aT = etp + ((size_t)((m0 >> 7) * 16) << 13);
    const ushort* bT = sw1tp + ((size_t)((n0 >> 7) * 16) << 13);
    mfma_tp<false>(aT, bT, nullptr, 16, As, Bs1, Bs3, acc1, acc3, tid);
    #pragma unroll
    for (int mi = 0; mi < 4; mi++) {
      #pragma unroll
      for (int r = 0; r < 4; r++) {
        const int row = m0 + wm * 64 + mi * 16 + quad * 4 + r;
        #pragma unroll
        for (int ni = 0; ni < 4; ni++) {
          const int col = n0 + wn * 64 + ni * 16 + lr;
          const float v = acc1[mi][ni][r] + sB1[col];
          const float sg = 1.0f / (1.0f + __expf(-v));
          hs_tp[tp_idx(row, col, 32)] = f2b(v * sg);
        }
      }
    }
  } else {                             // ---- routed SwiGLU front
    const int t = b - 512;
    const int mt = t >> 3;
    if (mt >= offp[NEXP + 1]) return;
    const int n0 = (t & 7) << 7;
    const int e = tbl[2 * mt], row0 = tbl[2 * mt + 1];
    const ushort* aT  = ag + ((size_t)((row0 >> 7) * 16) << 13);
    const ushort* b1T = w1tp + ((size_t)e << 20) + ((size_t)((n0 >> 7) * 16) << 13);
    const ushort* b3T = w3tp + ((size_t)e << 20) + ((size_t)((n0 >> 7) * 16) << 13);
    mfma_tp<true>(aT, b1T, b3T, 16, As, Bs1, Bs3, acc1, acc3, tid);
    #pragma unroll
    for (int mi = 0; mi < 4; mi++) {
      #pragma unroll
      for (int r = 0; r < 4; r++) {
        const int grow = row0 + wm * 64 + mi * 16 + quad * 4 + r;
        #pragma unroll
        for (int ni = 0; ni < 4; ni++) {
          const int col = n0 + wn * 64 + ni * 16 + lr;
          const float v1 = acc1[mi][ni][r] + B1[e * HID + col];
          const float v3 = acc3[mi][ni][r] + B3[e * HID + col];
          const float sg = 1.0f / (1.0f + __expf(-v1));
          h_tp[tp_idx(grow, col, 16)] = f2b(v1 * sg * v3);
        }
      }
    }
  }
}

// ---------------------------------------------------------------------------
// Stage 2, flat grid: b < 256 -> shared back; else routed back (table-driven).
// Both atomicAdd into zero-inited y. 32KB LDS x 4 blocks/CU = 128KB.
// ---------------------------------------------------------------------------
__launch_bounds__(256, 4)
__global__ void stage2(const ushort* __restrict__ h_tp, const ushort* __restrict__ hs_tp,
                       const ushort* __restrict__ w2tp, const ushort* __restrict__ sw2tp,
                       const float* __restrict__ B2, const float* __restrict__ sB2,
                       const int* __restrict__ cnt, const int* __restrict__ offp,
                       const int* __restrict__ tbl, const int* __restrict__ list,
                       const float* __restrict__ wl, float* __restrict__ y)
{
  __shared__ ushort As[8192], Bs[8192];
  const int tid = threadIdx.x;
  const int lane = tid & 63, w = tid >> 6;
  const int wm = w & 1, wn = w >> 1;
  const int quad = lane >> 4, lr = lane & 15;
  const int b = blockIdx.x;

  f4_t acc[4][4];
  const f4_t fz = {0.f, 0.f, 0.f, 0.f};
  #pragma unroll
  for (int i = 0; i < 4; i++)
    #pragma unroll
    for (int j = 0; j < 4; j++) acc[i][j] = fz;

  if (b < 256) {                       // ---- shared expert back (K=2048)
    const int m0 = (b >> 3) << 7;
    const int n0 = (b & 7) << 7;
    const ushort* aT = hs_tp + ((size_t)((m0 >> 7) * 32) << 13);
    const ushort* bT = sw2tp + ((size_t)((n0 >> 7) * 32) << 13);
    mfma_tp<false>(aT, bT, nullptr, 32, As, Bs, Bs, acc, acc, tid);
    #pragma unroll
    for (int mi = 0; mi < 4; mi++) {
      #pragma unroll
      for (int r = 0; r < 4; r++) {
        const int row = m0 + wm * 64 + mi * 16 + quad * 4 + r;
        float* yr = y + (size_t)row * DIM;
        #pragma unroll
        for (int ni = 0; ni < 4; ni++) {
          const int col = n0 + wn * 64 + ni * 16 + lr;
          atomicAdd(&yr[col], acc[mi][ni][r] + sB2[col]);
        }
      }
    }
  } else {                             // ---- routed back (K=1024)
    const int t = b - 256;
    const int mt = t >> 3;
    if (mt >= offp[NEXP + 1]) return;
    const int n0 = (t & 7) << 7;
    const int e = tbl[2 * mt], row0 = tbl[2 * mt + 1];
    const int ce = cnt[e];
    const int s0 = row0 - offp[e];
    const ushort* aT = h_tp + ((size_t)((row0 >> 7) * 16) << 13);
    const ushort* bT = w2tp + ((size_t)e << 20) + ((size_t)((n0 >> 7) * 16) << 13);
    mfma_tp<false>(aT, bT, nullptr, 16, As, Bs, Bs, acc, acc, tid);
    #pragma unroll
    for (int mi = 0; mi < 4; mi++) {
      #pragma unroll
      for (int r = 0; r < 4; r++) {
        const int rowl = s0 + wm * 64 + mi * 16 + quad * 4 + r;
        if (rowl < ce) {
          const int tok = list[e * T_TOK + rowl];
          const float wgt = wl[e * T_TOK + rowl];
          float* yr = y + (size_t)tok * DIM;
          #pragma unroll
          for (int ni = 0; ni < 4; ni++) {
            const int col = n0 + wn * 64 + ni * 16 + lr;
            atomicAdd(&yr[col], wgt * (acc[mi][ni][r] + B2[e * DIM + col]));
          }
        }
      }
    }
  }
}

// ---------------------------------------------------------------------------
// Launch
// ---------------------------------------------------------------------------
extern "C" void kernel_launch(void* const* d_in, const int* in_sizes, int n_in,
                              void* d_out, int out_size, void* d_ws, size_t ws_size,
                              hipStream_t stream)
{
  const float* emb = (const float*)d_in[0];
  const float* x   = (const float*)d_in[1];
  const float* gw  = (const float*)d_in[2];
  const float* W1  = (const float*)d_in[3];
  const float* B1  = (const float*)d_in[4];
  const float* W2  = (const float*)d_in[5];
  const float* B2  = (const float*)d_in[6];
  const float* W3  = (const float*)d_in[7];
  const float* B3  = (const float*)d_in[8];
  const float* sW1 = (const float*)d_in[9];
  const float* sB1 = (const float*)d_in[10];
  const float* sW2 = (const float*)d_in[11];
  const float* sB2 = (const float*)d_in[12];
  float* y = (float*)d_out;

  char* ws = (char*)d_ws;
  const size_t MB = 1024ULL * 1024ULL;
  ushort* embf  = (ushort*)(ws + 0);        // [4096][1024] flat
  ushort* xf    = (ushort*)(ws + 8 * MB);   // [4096][1024] flat
  ushort* etp   = (ushort*)(ws + 16 * MB);  // emb TP (KT=16)
  ushort* w1tp  = (ushort*)(ws + 24 * MB);  // [16] x TP [1024n][1024k]
  ushort* w3tp  = (ushort*)(ws + 56 * MB);
  ushort* w2tp  = (ushort*)(ws + 88 * MB);  // [16] x TP [1024n][1024k]
  ushort* sw1tp = (ushort*)(ws + 120 * MB); // TP [2048n][1024k]
  ushort* sw2tp = (ushort*)(ws + 124 * MB); // TP [1024n][2048k]
  ushort* ag    = (ushort*)(ws + 128 * MB); // gathered A, TP, <=10240 rows
  ushort* h_tp  = (ushort*)(ws + 148 * MB); // routed hidden, TP, <=10240 rows
  ushort* hs_tp = (ushort*)(ws + 168 * MB); // shared hidden, TP [4096][2048]
  int*   cnt    = (int*)(ws + 184 * MB);    // [16]
  int*   offp   = cnt + 16;                 // [18]  (offp[17] = #m-tiles)
  int*   tbl    = offp + 18;                // [2*MT_MAX]
  int*   list   = (int*)(ws + 184 * MB + 1024);
  float* wl     = (float*)(ws + 184 * MB + 1024 + 262144);

  hipMemsetAsync(cnt, 0, 64, stream);
  hipMemsetAsync(y, 0, (size_t)T_TOK * DIM * sizeof(float), stream);
  prep<<<PREP_BLOCKS, 256, 0, stream>>>(emb, x, gw, W1, W3, W2, sW1, sW2,
                                        embf, xf, etp, w1tp, w3tp, w2tp,
                                        sw1tp, sw2tp, cnt, list, wl);
  scan_offs<<<1, 64, 0, stream>>>(cnt, offp, tbl);
  gather_a<<<MT_MAX, 256, 0, stream>>>(embf, xf, cnt, offp, tbl, list, ag);
  stage1<<<512 + MT_MAX * 8, 256, 0, stream>>>(ag, etp, w1tp, w3tp, sw1tp,
                                               B1, B3, sB1, offp, tbl, h_tp, hs_tp);
  stage2<<<256 + MT_MAX * 8, 256, 0, stream>>>(h_tp, hs_tp, w2tp, sw2tp, B2, sB2,
                                               cnt, offp, tbl, list, wl, y);
}

// Round 7
// 556.857 us; speedup vs baseline: 2.0254x; 1.0698x over previous
//
#include <hip/hip_runtime.h>

// Problem constants (fixed by the reference)
#define T_TOK 4096   // B*S tokens
#define DIM   1024   // model dim D
#define HID   1024   // expert hidden H
#define NEXP  16     // routed experts
#define HSH   2048   // shared hidden = NSH*H
#define NIN   2      // experts that consume x instead of emb
#define MT_MAX 80    // max routed m-tiles: (8192 + 16*127)/128 rounded up

typedef __attribute__((ext_vector_type(8))) short bf8_t;  // 8 x bf16 (MFMA A/B frag)
typedef __attribute__((ext_vector_type(4))) float f4_t;   // 4 x f32  (MFMA C/D frag)

__device__ __forceinline__ ushort f2b(float f) {  // f32 -> bf16 RNE
  unsigned u = __float_as_uint(f);
  u = (u + 0x7FFFu + ((u >> 16) & 1u)) >> 16;
  return (ushort)u;
}

// ---------------------------------------------------------------------------
// Tile-packed (TP) layout: matrix [NR][NK] stored as 128x64 tiles, row-major
// tile grid (KT = NK/64 tiles per tile-row), 8192 elems (16KB) per tile,
// contiguous. Element (r,c) at r*64 + XOR-swizzled column (by r&7) so MFMA
// fragment ds_read_b128 are bank-conflict-free. DMA copies tiles verbatim.
// ---------------------------------------------------------------------------
__device__ __forceinline__ int tp_off(int r, int c) {
  return r * 64 + ((((c >> 3) ^ (r & 7)) << 3) | (c & 7));
}
__device__ __forceinline__ size_t tp_idx(int row, int col, int KT) {
  return ((size_t)((row >> 7) * KT + (col >> 6)) << 13) + tp_off(row & 127, col & 63);
}

// Async global->LDS DMA, 16B/lane; LDS dest is wave-uniform base + lane*16.
__device__ __forceinline__ void gl_lds16(const ushort* g, ushort* l) {
  __builtin_amdgcn_global_load_lds(
      (const __attribute__((address_space(1))) void*)g,
      (__attribute__((address_space(3))) void*)l, 16, 0, 0);
}

// ---------------------------------------------------------------------------
// TP MFMA K-loop: nkt tiles of K=64. Each wave DMA-stages a contiguous 4KB
// quarter of each 16KB tile. 4 waves: 64x64 C-quadrants via 16x16x32 MFMA.
// ---------------------------------------------------------------------------
template<bool DUAL>
__device__ __forceinline__ void mfma_tp(
    const ushort* __restrict__ aT, const ushort* __restrict__ b1T,
    const ushort* __restrict__ b3T, int nkt,
    ushort* As, ushort* Bs1, ushort* Bs3,
    f4_t acc1[4][4], f4_t acc3[4][4], int tid)
{
  const int lane = tid & 63, w = tid >> 6;
  const int wm = w & 1, wn = w >> 1;
  const int quad = lane >> 4, lr = lane & 15;
  const int soff = w << 11;          // wave's 2048-elem quarter
  const int l8 = lane * 8;

  for (int kt = 0; kt < nkt; kt++) {
    const size_t tb = (size_t)kt << 13;
    const ushort* ga = aT + tb + soff + l8;
    const ushort* gb = b1T + tb + soff + l8;
    #pragma unroll
    for (int d = 0; d < 4; d++) {
      gl_lds16(ga + (d << 9), As  + soff + (d << 9));
      gl_lds16(gb + (d << 9), Bs1 + soff + (d << 9));
    }
    if (DUAL) {
      const ushort* gc = b3T + tb + soff + l8;
      #pragma unroll
      for (int d = 0; d < 4; d++)
        gl_lds16(gc + (d << 9), Bs3 + soff + (d << 9));
    }
    __syncthreads();
    #pragma unroll
    for (int half = 0; half < 2; half++) {
      const int ch = (half << 2) + quad;   // k-chunk index 0..7
      bf8_t af[4];
      #pragma unroll
      for (int mi = 0; mi < 4; mi++) {
        const int r = wm * 64 + mi * 16 + lr;
        af[mi] = *(const bf8_t*)&As[r * 64 + ((ch ^ (r & 7)) << 3)];
      }
      #pragma unroll
      for (int ni = 0; ni < 4; ni++) {
        const int n = wn * 64 + ni * 16 + lr;
        bf8_t b1 = *(const bf8_t*)&Bs1[n * 64 + ((ch ^ (n & 7)) << 3)];
        #pragma unroll
        for (int mi = 0; mi < 4; mi++)
          acc1[mi][ni] = __builtin_amdgcn_mfma_f32_16x16x32_bf16(af[mi], b1, acc1[mi][ni], 0, 0, 0);
        if (DUAL) {
          bf8_t b3 = *(const bf8_t*)&Bs3[n * 64 + ((ch ^ (n & 7)) << 3)];
          #pragma unroll
          for (int mi = 0; mi < 4; mi++)
            acc3[mi][ni] = __builtin_amdgcn_mfma_f32_16x16x32_bf16(af[mi], b3, acc3[mi][ni], 0, 0, 0);
        }
      }
    }
    __syncthreads();
  }
}

// ---------------------------------------------------------------------------
// Band transpose+cast+TP-pack: src fp32 [R][C], band = 64 consecutive k-rows
// (one TP k-tile depth). Reads full-wave CONTIGUOUS 1KB row-chunks (lane i =
// float4 i of the row) -> HBM-friendly granule; casts to bf16 into LDS
// [64][264] (pad 8); Phase B: 4n x 8k register micro-transpose from
// ds_read_b64, stores TP 16B chunks.
// ---------------------------------------------------------------------------
__device__ __forceinline__ void tr_band(const float* __restrict__ src,
                                        ushort* __restrict__ dst,
                                        int R, int C, int band, int tid,
                                        ushort* ts)
{
  const int KT = R >> 6;
  const int k0g = band * 64;
  const int nchunk = C >> 8;
  for (int c = 0; c < nchunk; c++) {
    // Phase A: 64 rows x 256 cols fp32 -> bf16 LDS. Wave = one 1KB row chunk.
    #pragma unroll
    for (int i = 0; i < 16; i++) {
      const int idx = i * 256 + tid;          // 0..4095
      const int r = idx >> 6, c4 = idx & 63;  // row, float4-col
      const float4 v = *(const float4*)(src + (size_t)(k0g + r) * C + c * 256 + c4 * 4);
      ushort4 u;
      u.x = f2b(v.x); u.y = f2b(v.y); u.z = f2b(v.z); u.w = f2b(v.w);
      *(ushort4*)&ts[r * 264 + c4 * 4] = u;
    }
    __syncthreads();
    // Phase B: micro-transpose, 2 steps x (4n x 8k) per thread.
    #pragma unroll
    for (int s = 0; s < 2; s++) {
      const int m = s * 256 + tid;            // 0..511
      const int ng = m & 63, kc = m >> 6;     // n-group (4 n), k-chunk 0..7
      ushort vv[32];
      #pragma unroll
      for (int j = 0; j < 8; j++)
        *(ushort4*)&vv[j * 4] = *(const ushort4*)&ts[(kc * 8 + j) * 264 + ng * 4];
      #pragma unroll
      for (int i = 0; i < 4; i++) {
        ushort o[8];
        #pragma unroll
        for (int j = 0; j < 8; j++) o[j] = vv[j * 4 + i];
        const int n = c * 256 + ng * 4 + i;
        *(uint4*)&dst[tp_idx(n, k0g + kc * 8, KT)] = *(uint4*)o;
      }
    }
    __syncthreads();
  }
}

// ---------------------------------------------------------------------------
// MEGA-PREP flat dispatch:
//   [0,4096)        gate: fp32 softmax + top-2 -> per-token (e0,e1,w0,w1)
//   [4096,5120)     cast emb+x -> bf16 flat (+ TP emb)
//   [5120,5888)     W1/W3/W2 band transpose (48 slices x 16 bands)
//   [5888,5904)     sW1 bands (R=1024,C=2048)
//   [5904,5936)     sW2 bands (R=2048,C=1024)
// ---------------------------------------------------------------------------
#define PREP_BLOCKS 5936
__global__ void prep(const float* __restrict__ emb, const float* __restrict__ x_,
                     const float* __restrict__ gw,
                     const float* __restrict__ W1, const float* __restrict__ W3,
                     const float* __restrict__ W2,
                     const float* __restrict__ sW1, const float* __restrict__ sW2,
                     ushort* __restrict__ embf, ushort* __restrict__ xf,
                     ushort* __restrict__ etp,
                     ushort* __restrict__ w1tp, ushort* __restrict__ w3tp,
                     ushort* __restrict__ w2tp,
                     ushort* __restrict__ sw1tp, ushort* __restrict__ sw2tp,
                     int* __restrict__ eA, int* __restrict__ eB,
                     float* __restrict__ wA, float* __restrict__ wB)
{
  __shared__ ushort smem[64 * 264];   // 33792 B; reused as fp32 scratch by gate
  const int b = blockIdx.x;
  const int t = threadIdx.x;

  if (b < 4096) {
    // ---------------- gate (no global atomics) ----------------
    float* se = (float*)smem;               // [1024]
    float* sc = (float*)smem + DIM;         // [16]
    const int tok = b;
    ((float4*)se)[t] = ((const float4*)(emb + (size_t)tok * DIM))[t];
    __syncthreads();
    const int e = t >> 4, l = t & 15;
    const float* g = gw + e * DIM + l * 4;
    const float* s = se + l * 4;
    float p = 0.f;
    #pragma unroll
    for (int j = 0; j < 16; j++) {
      const float4 gv = *(const float4*)(g + j * 64);
      const float4 sv = *(const float4*)(s + j * 64);
      p += gv.x * sv.x + gv.y * sv.y + gv.z * sv.z + gv.w * sv.w;
    }
    p += __shfl_xor(p, 1); p += __shfl_xor(p, 2);
    p += __shfl_xor(p, 4); p += __shfl_xor(p, 8);
    if (l == 0) sc[e] = p;
    __syncthreads();
    if (t == 0) {
      float m = sc[0];
      #pragma unroll
      for (int j = 1; j < NEXP; j++) m = fmaxf(m, sc[j]);
      float pr[NEXP]; float sum = 0.f;
      #pragma unroll
      for (int j = 0; j < NEXP; j++) { pr[j] = __expf(sc[j] - m); sum += pr[j]; }
      const float inv = 1.0f / sum;
      int i0 = 0; float b0 = pr[0];
      #pragma unroll
      for (int j = 1; j < NEXP; j++) if (pr[j] > b0) { b0 = pr[j]; i0 = j; }
      int i1 = -1; float b1 = -1.f;
      #pragma unroll
      for (int j = 0; j < NEXP; j++) if (j != i0 && pr[j] > b1) { b1 = pr[j]; i1 = j; }
      eA[tok] = i0; wA[tok] = b0 * inv;
      eB[tok] = i1; wB[tok] = b1 * inv;
    }
  } else if (b < 5120) {
    // ---------------- cast emb + x ----------------
    const int NC = (T_TOK * DIM) / 8;
    const int c0 = (b - 4096) * 256 + t;
    for (int c = c0; c < 2 * NC; c += 1024 * 256) {
      const bool isE = c < NC;
      const int g = (isE ? c : c - NC) << 3;
      const float* src = isE ? emb : x_;
      const float4 v0 = *(const float4*)(src + g);
      const float4 v1 = *(const float4*)(src + g + 4);
      ushort tt[8];
      tt[0] = f2b(v0.x); tt[1] = f2b(v0.y); tt[2] = f2b(v0.z); tt[3] = f2b(v0.w);
      tt[4] = f2b(v1.x); tt[5] = f2b(v1.y); tt[6] = f2b(v1.z); tt[7] = f2b(v1.w);
      ushort* flat = isE ? embf : xf;
      *(uint4*)(flat + g) = *(uint4*)tt;
      if (isE) {
        const int row = g >> 10, col = g & 1023;
        *(uint4*)&etp[tp_idx(row, col, 16)] = *(uint4*)tt;
      }
    }
  } else if (b < 5888) {
    // ---------------- W1/W3/W2 bands ----------------
    const int r = b - 5120;
    const int z = r >> 4, band = r & 15;
    const float* src = (z < 16) ? W1 : (z < 32) ? W3 : W2;
    ushort* dst = (z < 16) ? w1tp : (z < 32) ? w3tp : w2tp;
    tr_band(src + ((size_t)(z & 15) << 20), dst + ((size_t)(z & 15) << 20),
            1024, 1024, band, t, smem);
  } else if (b < 5904) {
    tr_band(sW1, sw1tp, DIM, HSH, b - 5888, t, smem);
  } else {
    tr_band(sW2, sw2tp, HSH, DIM, b - 5904, t, smem);
  }
}

// ---------------------------------------------------------------------------
// Build per-expert compact lists from per-token top-2 (deterministic, no
// global atomics): one block per expert, ballot prefix over 16 rounds.
// ---------------------------------------------------------------------------
__global__ void build_lists(const int* __restrict__ eA, const int* __restrict__ eB,
                            const float* __restrict__ wA, const float* __restrict__ wB,
                            int* __restrict__ cnt, int* __restrict__ list,
                            float* __restrict__ wl)
{
  const int e = blockIdx.x;
  __shared__ int wsum[4];
  __shared__ int sbase;
  const int tid = threadIdx.x;
  const int lane = tid & 63, wv = tid >> 6;
  if (tid == 0) sbase = 0;
  __syncthreads();
  for (int r = 0; r < 16; r++) {
    const int tk = r * 256 + tid;
    const int a = eA[tk], bb = eB[tk];
    const bool m = (a == e) || (bb == e);
    const float w = (a == e) ? wA[tk] : wB[tk];
    const unsigned long long bal = __ballot(m);
    const int pw = __popcll(bal & ((1ULL << lane) - 1ULL));
    if (lane == 63) wsum[wv] = pw + (m ? 1 : 0);
    __syncthreads();
    int base = sbase;
    for (int k = 0; k < wv; k++) base += wsum[k];
    if (m) {
      const int pos = base + pw;
      list[e * T_TOK + pos] = tk;
      wl[e * T_TOK + pos] = w;
    }
    __syncthreads();
    if (tid == 0) sbase += wsum[0] + wsum[1] + wsum[2] + wsum[3];
    __syncthreads();
  }
  if (tid == 0) cnt[e] = sbase;
}

// offp[e] = 128-aligned prefix sum; offp[17] = #m-tiles; tbl[2*mt] = {e, row0}
__global__ void scan_offs(const int* __restrict__ cnt, int* __restrict__ offp,
                          int* __restrict__ tbl)
{
  if (blockIdx.x == 0 && threadIdx.x == 0) {
    int a = 0, nm = 0;
    for (int e = 0; e < NEXP; e++) {
      offp[e] = a;
      const int c = (cnt[e] + 127) & ~127;
      for (int r = 0; r < c; r += 128) { tbl[2 * nm] = e; tbl[2 * nm + 1] = a + r; nm++; }
      a += c;
    }
    offp[NEXP] = a;
    offp[NEXP + 1] = nm;
  }
}

// ---------------------------------------------------------------------------
// Gather routed A rows into TP compact form (pad slots -> zeros). Grid
// MT_MAX x 8: mt = b>>3, 128-col slice = b&7.
// ---------------------------------------------------------------------------
__global__ void gather_a(const ushort* __restrict__ embf, const ushort* __restrict__ xf,
                         const int* __restrict__ cnt, const int* __restrict__ offp,
                         const int* __restrict__ tbl, const int* __restrict__ list,
                         ushort* __restrict__ ag)
{
  const int mt = blockIdx.x >> 3;
  if (mt >= offp[NEXP + 1]) return;
  const int sl = blockIdx.x & 7;
  const int e = tbl[2 * mt], row0 = tbl[2 * mt + 1];
  const int ce = cnt[e];
  const int s0 = row0 - offp[e];
  const ushort* src = (e < NIN) ? xf : embf;
  const int tid = threadIdx.x;
  #pragma unroll
  for (int rep = 0; rep < 8; rep++) {
    const int lin = rep * 256 + tid;        // 128 rows x 16 chunks
    const int r = lin >> 4, c8 = (sl * 128) + ((lin & 15) << 3);
    const int s = s0 + r;
    uint4 v = make_uint4(0u, 0u, 0u, 0u);
    if (s < ce) {
      const int tok = list[e * T_TOK + s];
      v = *(const uint4*)&src[(size_t)tok * DIM + c8];
    }
    *(uint4*)&ag[tp_idx(row0 + r, c8, 16)] = v;
  }
}

// ---------------------------------------------------------------------------
// Stage 1, flat grid: b < 512 -> shared front (hs TP); else routed SwiGLU
// front (h TP), table-driven m-tiles. 48KB LDS x 3 blocks/CU.
// ---------------------------------------------------------------------------
__launch_bounds__(256, 3)
__global__ void stage1(const ushort* __restrict__ ag, const ushort* __restrict__ etp,
                       const ushort* __restrict__ w1tp, const ushort* __restrict__ w3tp,
                       const ushort* __restrict__ sw1tp,
                       const float* __restrict__ B1, const float* __restrict__ B3,
                       const float* __restrict__ sB1,
                       const int* __restrict__ offp, const int* __restrict__ tbl,
                       ushort* __restrict__ h_tp, ushort* __restrict__ hs_tp)
{
  __shared__ ushort As[8192], Bs1[8192], Bs3[8192];
  const int tid = threadIdx.x;
  const int lane = tid & 63, w = tid >> 6;
  const int wm = w & 1, wn = w >> 1;
  const int quad = lane >> 4, lr = lane & 15;
  const int b = blockIdx.x;

  f4_t acc1[4][4], acc3[4][4];
  const f4_t fz = {0.f, 0.f, 0.f, 0.f};
  #pragma unroll
  for (int i = 0; i < 4; i++)
    #pragma unroll
    for (int j = 0; j < 4; j++) { acc1[i][j] = fz; acc3[i][j] = fz; }

  if (b < 512) {                       // ---- shared expert front: all real
    const int m0 = (b >> 4) << 7;
    const int n0 = (b & 15) << 7;
    const ushort* aT = etp + ((size_t)((m0 >> 7) * 16) << 13);
    const ushort* bT = sw1tp + ((size_t)((n0 >> 7) * 16) << 13);
    mfma_tp<false>(aT, bT, nullptr, 16, As, Bs1, Bs3, acc1, acc3, tid);
    #pragma unroll
    for (int mi = 0; mi < 4; mi++) {
      #pragma unroll
      for (int r = 0; r < 4; r++) {
        const int row = m0 + wm * 64 + mi * 16 + quad * 4 + r;
        #pragma unroll
        for (int ni = 0; ni < 4; ni++) {
          const int col = n0 + wn * 64 + ni * 16 + lr;
          const float v = acc1[mi][ni][r] + sB1[col];
          const float sg = 1.0f / (1.0f + __expf(-v));
          hs_tp[tp_idx(row, col, 32)] = f2b(v * sg);
        }
      }
    }
  } else {                             // ---- routed SwiGLU front
    const int t = b - 512;
    const int mt = t >> 3;
    if (mt >= offp[NEXP + 1]) return;
    const int n0 = (t & 7) << 7;
    const int e = tbl[2 * mt], row0 = tbl[2 * mt + 1];
    const ushort* aT  = ag + ((size_t)((row0 >> 7) * 16) << 13);
    const ushort* b1T = w1tp + ((size_t)e << 20) + ((size_t)((n0 >> 7) * 16) << 13);
    const ushort* b3T = w3tp + ((size_t)e << 20) + ((size_t)((n0 >> 7) * 16) << 13);
    mfma_tp<true>(aT, b1T, b3T, 16, As, Bs1, Bs3, acc1, acc3, tid);
    #pragma unroll
    for (int mi = 0; mi < 4; mi++) {
      #pragma unroll
      for (int r = 0; r < 4; r++) {
        const int grow = row0 + wm * 64 + mi * 16 + quad * 4 + r;
        #pragma unroll
        for (int ni = 0; ni < 4; ni++) {
          const int col = n0 + wn * 64 + ni * 16 + lr;
          const float v1 = acc1[mi][ni][r] + B1[e * HID + col];
          const float v3 = acc3[mi][ni][r] + B3[e * HID + col];
          const float sg = 1.0f / (1.0f + __expf(-v1));
          h_tp[tp_idx(grow, col, 16)] = f2b(v1 * sg * v3);
        }
      }
    }
  }
}

// ---------------------------------------------------------------------------
// Stage 2, flat grid: b < 256 -> shared back; else routed back (table-driven).
// Both atomicAdd into zero-inited y. 32KB LDS x 4 blocks/CU.
// ---------------------------------------------------------------------------
__launch_bounds__(256, 4)
__global__ void stage2(const ushort* __restrict__ h_tp, const ushort* __restrict__ hs_tp,
                       const ushort* __restrict__ w2tp, const ushort* __restrict__ sw2tp,
                       const float* __restrict__ B2, const float* __restrict__ sB2,
                       const int* __restrict__ cnt, const int* __restrict__ offp,
                       const int* __restrict__ tbl, const int* __restrict__ list,
                       const float* __restrict__ wl, float* __restrict__ y)
{
  __shared__ ushort As[8192], Bs[8192];
  const int tid = threadIdx.x;
  const int lane = tid & 63, w = tid >> 6;
  const int wm = w & 1, wn = w >> 1;
  const int quad = lane >> 4, lr = lane & 15;
  const int b = blockIdx.x;

  f4_t acc[4][4];
  const f4_t fz = {0.f, 0.f, 0.f, 0.f};
  #pragma unroll
  for (int i = 0; i < 4; i++)
    #pragma unroll
    for (int j = 0; j < 4; j++) acc[i][j] = fz;

  if (b < 256) {                       // ---- shared expert back (K=2048)
    const int m0 = (b >> 3) << 7;
    const int n0 = (b & 7) << 7;
    const ushort* aT = hs_tp + ((size_t)((m0 >> 7) * 32) << 13);
    const ushort* bT = sw2tp + ((size_t)((n0 >> 7) * 32) << 13);
    mfma_tp<false>(aT, bT, nullptr, 32, As, Bs, Bs, acc, acc, tid);
    #pragma unroll
    for (int mi = 0; mi < 4; mi++) {
      #pragma unroll
      for (int r = 0; r < 4; r++) {
        const int row = m0 + wm * 64 + mi * 16 + quad * 4 + r;
        float* yr = y + (size_t)row * DIM;
        #pragma unroll
        for (int ni = 0; ni < 4; ni++) {
          const int col = n0 + wn * 64 + ni * 16 + lr;
          atomicAdd(&yr[col], acc[mi][ni][r] + sB2[col]);
        }
      }
    }
  } else {                             // ---- routed back (K=1024)
    const int t = b - 256;
    const int mt = t >> 3;
    if (mt >= offp[NEXP + 1]) return;
    const int n0 = (t & 7) << 7;
    const int e = tbl[2 * mt], row0 = tbl[2 * mt + 1];
    const int ce = cnt[e];
    const int s0 = row0 - offp[e];
    const ushort* aT = h_tp + ((size_t)((row0 >> 7) * 16) << 13);
    const ushort* bT = w2tp + ((size_t)e << 20) + ((size_t)((n0 >> 7) * 16) << 13);
    mfma_tp<false>(aT, bT, nullptr, 16, As, Bs, Bs, acc, acc, tid);
    #pragma unroll
    for (int mi = 0; mi < 4; mi++) {
      #pragma unroll
      for (int r = 0; r < 4; r++) {
        const int rowl = s0 + wm * 64 + mi * 16 + quad * 4 + r;
        if (rowl < ce) {
          const int tok = list[e * T_TOK + rowl];
          const float wgt = wl[e * T_TOK + rowl];
          float* yr = y + (size_t)tok * DIM;
          #pragma unroll
          for (int ni = 0; ni < 4; ni++) {
            const int col = n0 + wn * 64 + ni * 16 + lr;
            atomicAdd(&yr[col], wgt * (acc[mi][ni][r] + B2[e * DIM + col]));
          }
        }
      }
    }
  }
}

// ---------------------------------------------------------------------------
// Launch
// ---------------------------------------------------------------------------
extern "C" void kernel_launch(void* const* d_in, const int* in_sizes, int n_in,
                              void* d_out, int out_size, void* d_ws, size_t ws_size,
                              hipStream_t stream)
{
  const float* emb = (const float*)d_in[0];
  const float* x   = (const float*)d_in[1];
  const float* gw  = (const float*)d_in[2];
  const float* W1  = (const float*)d_in[3];
  const float* B1  = (const float*)d_in[4];
  const float* W2  = (const float*)d_in[5];
  const float* B2  = (const float*)d_in[6];
  const float* W3  = (const float*)d_in[7];
  const float* B3  = (const float*)d_in[8];
  const float* sW1 = (const float*)d_in[9];
  const float* sB1 = (const float*)d_in[10];
  const float* sW2 = (const float*)d_in[11];
  const float* sB2 = (const float*)d_in[12];
  float* y = (float*)d_out;

  char* ws = (char*)d_ws;
  const size_t MB = 1024ULL * 1024ULL;
  ushort* embf  = (ushort*)(ws + 0);        // [4096][1024] flat
  ushort* xf    = (ushort*)(ws + 8 * MB);   // [4096][1024] flat
  ushort* etp   = (ushort*)(ws + 16 * MB);  // emb TP (KT=16)
  ushort* w1tp  = (ushort*)(ws + 24 * MB);  // [16] x TP [1024n][1024k]
  ushort* w3tp  = (ushort*)(ws + 56 * MB);
  ushort* w2tp  = (ushort*)(ws + 88 * MB);  // [16] x TP [1024n][1024k]
  ushort* sw1tp = (ushort*)(ws + 120 * MB); // TP [2048n][1024k]
  ushort* sw2tp = (ushort*)(ws + 124 * MB); // TP [1024n][2048k]
  ushort* ag    = (ushort*)(ws + 128 * MB); // gathered A, TP, <=10240 rows
  ushort* h_tp  = (ushort*)(ws + 148 * MB); // routed hidden, TP, <=10240 rows
  ushort* hs_tp = (ushort*)(ws + 168 * MB); // shared hidden, TP [4096][2048]
  int*   cnt    = (int*)(ws + 184 * MB);    // [16]
  int*   offp   = cnt + 16;                 // [18]  (offp[17] = #m-tiles)
  int*   tbl    = offp + 18;                // [2*MT_MAX]
  int*   list   = (int*)(ws + 184 * MB + 1024);            // [16][4096]
  float* wl     = (float*)(ws + 184 * MB + 1024 + 262144); // [16][4096]
  int*   eA     = (int*)(ws + 185 * MB);    // [4096]
  int*   eB     = eA + T_TOK;
  float* wA     = (float*)(eB + T_TOK);
  float* wB     = wA + T_TOK;

  hipMemsetAsync(y, 0, (size_t)T_TOK * DIM * sizeof(float), stream);
  prep<<<PREP_BLOCKS, 256, 0, stream>>>(emb, x, gw, W1, W3, W2, sW1, sW2,
                                        embf, xf, etp, w1tp, w3tp, w2tp,
                                        sw1tp, sw2tp, eA, eB, wA, wB);
  build_lists<<<NEXP, 256, 0, stream>>>(eA, eB, wA, wB, cnt, list, wl);
  scan_offs<<<1, 64, 0, stream>>>(cnt, offp, tbl);
  gather_a<<<MT_MAX * 8, 256, 0, stream>>>(embf, xf, cnt, offp, tbl, list, ag);
  stage1<<<512 + MT_MAX * 8, 256, 0, stream>>>(ag, etp, w1tp, w3tp, sw1tp,
                                               B1, B3, sB1, offp, tbl, h_tp, hs_tp);
  stage2<<<256 + MT_MAX * 8, 256, 0, stream>>>(h_tp, hs_tp, w2tp, sw2tp, B2, sB2,
                                               cnt, offp, tbl, list, wl, y);
}